// Round 8
// baseline (287.135 us; speedup 1.0000x reference)
//
#include <hip/hip_runtime.h>
#include <hip/hip_bf16.h>

typedef __attribute__((ext_vector_type(8))) short short8;
typedef __attribute__((ext_vector_type(4))) short bfx4;
typedef __attribute__((ext_vector_type(4))) float floatx4;
typedef __attribute__((ext_vector_type(4))) __fp16 h4_t;
typedef __attribute__((ext_vector_type(2))) __fp16 h2_t;
typedef __attribute__((ext_vector_type(8))) __fp16 h8_t;

#define BATCH 4
#define SEQ 2048
#define D_MODEL 1024
#define NH 16
#define HD 64
#define ELEMS 8388608   // B*S*D = 4*2048*1024
#define WELEMS 1048576  // 1024*1024

// fp32 -> bf16 round-to-nearest-even
__device__ __forceinline__ unsigned short f2bf(float f) {
    union { float f; unsigned u; } x; x.f = f;
    unsigned r = x.u + 0x7FFFu + ((x.u >> 16) & 1u);
    return (unsigned short)(r >> 16);
}
__device__ __forceinline__ unsigned short f2h(float f) {
    union { __fp16 h; unsigned short u; } x;
    x.h = (__fp16)f;
    return x.u;
}

#if __has_builtin(__builtin_amdgcn_exp2f)
__device__ __forceinline__ float fexp2(float x) { return __builtin_amdgcn_exp2f(x); }
#else
__device__ __forceinline__ float fexp2(float x) { return exp2f(x); }
#endif

// async global->LDS, 16B per lane; HW dest = wave-uniform base + lane*16
__device__ __forceinline__ void gll16(const void* g, const void* l) {
    __builtin_amdgcn_global_load_lds(
        (const __attribute__((address_space(1))) void*)g,
        (__attribute__((address_space(3))) void*)l,
        16, 0, 0);
}

// NOTE (session post-mortems):
//  - R1: 8-phase 256^2 counted-vmcnt GEMM port regressed. Abandoned.
//  - R2: double-buffered attn regressed: compiler drains vmcnt(0) before the
//    first ds_read of the other buffer. Do not software-pipeline
//    global_load_lds here.
//  - R3: 128^2 GEMM tiles > 128x256 at K=1024 (total 317->302).
//  - R4: attn7 (4 acc sets + 8 bq) spilled at the 128-VGPR cap. Register
//    budget is the hard wall; FETCH/WRITE blowup is the spill signature.
//  - R5: attn8 (2 acc sets, K/V-read reuse across 2 Q-frags): 107us. 281.8.
//  - R6: attn XCD swizzle WIN (107->86.5us, FETCH 110->24.6MB). GEMM XCD
//    swizzle REGRESSED (resident-set arithmetic was wrong-grained; default
//    dispatch already fine at the K-slice granularity). Reverted.
//  - R7: recombined proven states -> 268.5us. attn8 86.7 stable.
//  - R8 (this round): attn9 KVBLK 128->256: same "more compute per staged
//    tile at CONSTANT register footprint" lever as R5, on the KV axis.
//    Drain events 136->72 per bh; registers unchanged (only inner loop
//    doubled); 64KB LDS -> 2 blocks/CU; odd-j blocks skip their fully-
//    masked partner sub-tile.

// ---------------------------------------------------------------------------
// cvt: x (8M), wq|wk|wv (3M, concatenated), wo (1M) fp32 -> bf16
// ---------------------------------------------------------------------------
__global__ __launch_bounds__(256)
void cvt_kernel(const float* __restrict__ x,  const float* __restrict__ wq,
                const float* __restrict__ wk, const float* __restrict__ wv,
                const float* __restrict__ wo,
                unsigned short* __restrict__ xbf,
                unsigned short* __restrict__ wqkv,
                unsigned short* __restrict__ wobf)
{
    size_t idx = ((size_t)blockIdx.x * 256 + threadIdx.x) * 8;
    const float* src; unsigned short* dst; size_t off;
    if (idx < (size_t)ELEMS)                    { src = x;  dst = xbf;             off = idx; }
    else if (idx < (size_t)ELEMS + WELEMS)      { src = wq; dst = wqkv;            off = idx - ELEMS; }
    else if (idx < (size_t)ELEMS + 2 * WELEMS)  { src = wk; dst = wqkv + WELEMS;   off = idx - ELEMS - WELEMS; }
    else if (idx < (size_t)ELEMS + 3 * WELEMS)  { src = wv; dst = wqkv + 2*WELEMS; off = idx - ELEMS - 2*WELEMS; }
    else                                        { src = wo; dst = wobf;            off = idx - ELEMS - 3*WELEMS; }
    floatx4 a = *(const floatx4*)(src + off);
    floatx4 b = *(const floatx4*)(src + off + 4);
    short8 v;
#pragma unroll
    for (int d = 0; d < 4; d++) { v[d] = (short)f2bf(a[d]); v[4+d] = (short)f2bf(b[d]); }
    *(short8*)(dst + off) = v;
}

// ---------------------------------------------------------------------------
// QKV GEMM, 128x128 tile (R3/R5/R7 proven, default 2D dispatch): A=x_bf
// [8192,1024], B=wqkv_bf [3072,1024] (NT), staged via global_load_lds with
// inverse-XOR-swizzled source. BK=64, 32 KiB LDS. Grid (64,24).
// ---------------------------------------------------------------------------
__global__ __launch_bounds__(256, 2)
void gemm_qkv3_kernel(const unsigned short* __restrict__ A,
                      const unsigned short* __restrict__ B,
                      unsigned short* __restrict__ Qb,
                      unsigned short* __restrict__ Kb,
                      unsigned short* __restrict__ Vb)
{
    __shared__ __align__(16) unsigned short As[128 * 64];
    __shared__ __align__(16) unsigned short Bs[128 * 64];

    const int t = threadIdx.x;
    const int wave = t >> 6, lane = t & 63;
    const int lm = lane & 15, lq = lane >> 4;
    const int wrow = (wave >> 1) * 64, wcol = (wave & 1) * 64;
    const int m0 = blockIdx.x * 128, n0 = blockIdx.y * 128;
    const int lrow = lane >> 3, lg = lane & 7;
    const int gsw = lg ^ lrow;

    floatx4 acc[4][4] = {};

    for (int k0 = 0; k0 < 1024; k0 += 64) {
        __syncthreads();
#pragma unroll
        for (int i = 0; i < 4; i++) {
            int rows8 = wave * 32 + i * 8;
            gll16(A + (size_t)(m0 + rows8 + lrow) * 1024 + k0 + gsw * 8, As + rows8 * 64);
            gll16(B + (size_t)(n0 + rows8 + lrow) * 1024 + k0 + gsw * 8, Bs + rows8 * 64);
        }
        __syncthreads();

#pragma unroll
        for (int c = 0; c < 2; c++) {
            short8 af[4], bfr[4];
#pragma unroll
            for (int i = 0; i < 4; i++) {
                int ra = wrow + i * 16 + lm;
                int g = c * 4 + lq;
                af[i] = *(const short8*)(As + (ra * 8 + (g ^ (ra & 7))) * 8);
            }
#pragma unroll
            for (int j = 0; j < 4; j++) {
                int rb = wcol + j * 16 + lm;
                int g = c * 4 + lq;
                bfr[j] = *(const short8*)(Bs + (rb * 8 + (g ^ (rb & 7))) * 8);
            }
#pragma unroll
            for (int i = 0; i < 4; i++)
#pragma unroll
                for (int j = 0; j < 4; j++)
                    acc[i][j] = __builtin_amdgcn_mfma_f32_16x16x32_bf16(
                        af[i], bfr[j], acc[i][j], 0, 0, 0);
        }
    }

    const int z = n0 >> 10;   // 0=Q 1=K 2=V, uniform per block
#pragma unroll
    for (int i = 0; i < 4; i++)
#pragma unroll
        for (int j = 0; j < 4; j++)
#pragma unroll
            for (int r = 0; r < 4; r++) {
                int gm = m0 + wrow + i * 16 + lq * 4 + r;
                int gn = n0 + wcol + j * 16 + lm;
                int nl = gn & 1023, h = nl >> 6, d = nl & 63;
                int b = gm >> 11, s = gm & 2047;
                float v = acc[i][j][r];
                size_t bh = (size_t)(b * NH + h);
                if (z == 0)      Qb[(bh * SEQ + s) * HD + d] = f2bf(v);
                else if (z == 1) Kb[(bh * SEQ + s) * HD + d] = f2bf(v);
                else             Vb[(bh * HD + d) * SEQ + s] = f2h(v);
            }
}

// ---------------------------------------------------------------------------
// Output projection, 128x128 tile (R3/R5/R7 proven, default 2D dispatch):
// A=Ob bf16 [8192,1024], B=wo_bf [1024,1024] -> fp32. Grid (64,8).
// ---------------------------------------------------------------------------
__global__ __launch_bounds__(256, 2)
void gemm_out3_kernel(const unsigned short* __restrict__ A,
                      const unsigned short* __restrict__ B,
                      float* __restrict__ Out)
{
    __shared__ __align__(16) unsigned short As[128 * 64];
    __shared__ __align__(16) unsigned short Bs[128 * 64];

    const int t = threadIdx.x;
    const int wave = t >> 6, lane = t & 63;
    const int lm = lane & 15, lq = lane >> 4;
    const int wrow = (wave >> 1) * 64, wcol = (wave & 1) * 64;
    const int m0 = blockIdx.x * 128, n0 = blockIdx.y * 128;
    const int lrow = lane >> 3, lg = lane & 7;
    const int gsw = lg ^ lrow;

    floatx4 acc[4][4] = {};

    for (int k0 = 0; k0 < 1024; k0 += 64) {
        __syncthreads();
#pragma unroll
        for (int i = 0; i < 4; i++) {
            int rows8 = wave * 32 + i * 8;
            gll16(A + (size_t)(m0 + rows8 + lrow) * 1024 + k0 + gsw * 8, As + rows8 * 64);
            gll16(B + (size_t)(n0 + rows8 + lrow) * 1024 + k0 + gsw * 8, Bs + rows8 * 64);
        }
        __syncthreads();

#pragma unroll
        for (int c = 0; c < 2; c++) {
            short8 af[4], bfr[4];
#pragma unroll
            for (int i = 0; i < 4; i++) {
                int ra = wrow + i * 16 + lm;
                int g = c * 4 + lq;
                af[i] = *(const short8*)(As + (ra * 8 + (g ^ (ra & 7))) * 8);
            }
#pragma unroll
            for (int j = 0; j < 4; j++) {
                int rb = wcol + j * 16 + lm;
                int g = c * 4 + lq;
                bfr[j] = *(const short8*)(Bs + (rb * 8 + (g ^ (rb & 7))) * 8);
            }
#pragma unroll
            for (int i = 0; i < 4; i++)
#pragma unroll
                for (int j = 0; j < 4; j++)
                    acc[i][j] = __builtin_amdgcn_mfma_f32_16x16x32_bf16(
                        af[i], bfr[j], acc[i][j], 0, 0, 0);
        }
    }

#pragma unroll
    for (int i = 0; i < 4; i++)
#pragma unroll
        for (int j = 0; j < 4; j++)
#pragma unroll
            for (int r = 0; r < 4; r++) {
                int gm = m0 + wrow + i * 16 + lq * 4 + r;
                int gn = n0 + wcol + j * 16 + lm;
                Out[(size_t)gm * D_MODEL + gn] = acc[i][j][r];
            }
}

// ---------------------------------------------------------------------------
// Flash attention v9: KVBLK=256 (two 128-key sub-tiles per staged tile).
// Same 2 Q-frags/wave + XCD swizzle as attn8 (R5/R6 proven). Drain events
// halve (72 vs 136 per bh); registers unchanged. LDS 64KB (2 blocks/CU).
// Sub-tile s==j gets the causal mask (module bug: attend only keys > q);
// odd-j blocks skip their fully-masked partner sub-tile s==j-1.
// Q,K bf16 [b,h,s,d]; V f16 [b,h,d,s]; O bf16 [b,s,1024].
// Row 2047 (l=0 -> NaN) overwritten by row2047_kernel afterwards.
// V LDS swizzle: 256-key rows = 32 x 16B chunks; chunk c stored at
// c ^ ((row&15)<<1); read g16 ^ (lm<<1). K swizzle unchanged (8-chunk rows).
// ---------------------------------------------------------------------------
#define PROCESS_SUB(SUB, DOMASK, T)                                            \
    do {                                                                       \
        _Pragma("unroll")                                                      \
        for (int jt = 0; jt < 8; jt++) {                                       \
            floatx4 sc0 = {}, sc1 = {};                                        \
            _Pragma("unroll")                                                  \
            for (int c = 0; c < 2; c++) {                                      \
                int row_ = (SUB) * 128 + jt * 16 + lm;                         \
                int g_ = c * 4 + lq;                                           \
                short8 kf = *(const short8*)(Ks + (row_ * 8 + (g_ ^ (row_ & 7))) * 8); \
                sc0 = __builtin_amdgcn_mfma_f32_16x16x32_bf16(kf, bq0[c], sc0, 0, 0, 0); \
                sc1 = __builtin_amdgcn_mfma_f32_16x16x32_bf16(kf, bq1[c], sc1, 0, 0, 0); \
            }                                                                  \
            if (DOMASK) {                                                      \
                _Pragma("unroll")                                              \
                for (int r = 0; r < 4; r++) {                                  \
                    int kj = (T) * 256 + (SUB) * 128 + jt * 16 + lq * 4 + r;   \
                    if (!(kj > q0)) sc0[r] = -3.2e10f;                         \
                    if (!(kj > q1)) sc1[r] = -3.2e10f;                         \
                }                                                              \
            }                                                                  \
            float p00 = fexp2(sc0[0] * kA), p01 = fexp2(sc0[1] * kA);          \
            float p02 = fexp2(sc0[2] * kA), p03 = fexp2(sc0[3] * kA);          \
            float p10 = fexp2(sc1[0] * kA), p11 = fexp2(sc1[1] * kA);          \
            float p12 = fexp2(sc1[2] * kA), p13 = fexp2(sc1[3] * kA);          \
            l0 += (p00 + p01) + (p02 + p03);                                   \
            l1 += (p10 + p11) + (p12 + p13);                                   \
            h2_t a0_ = __builtin_amdgcn_cvt_pkrtz(p00, p01);                   \
            h2_t b0_ = __builtin_amdgcn_cvt_pkrtz(p02, p03);                   \
            h2_t a1_ = __builtin_amdgcn_cvt_pkrtz(p10, p11);                   \
            h2_t b1_ = __builtin_amdgcn_cvt_pkrtz(p12, p13);                   \
            h4_t pf0, pf1;                                                     \
            pf0[0] = a0_[0]; pf0[1] = a0_[1]; pf0[2] = b0_[0]; pf0[3] = b0_[1];\
            pf1[0] = a1_[0]; pf1[1] = a1_[1]; pf1[2] = b1_[0]; pf1[3] = b1_[1];\
            _Pragma("unroll")                                                  \
            for (int jd = 0; jd < 4; jd++) {                                   \
                int rowv_ = jd * 16 + lm;                                      \
                int g16_ = (SUB) * 16 + jt * 2 + (lq >> 1);                    \
                int slot_ = rowv_ * 32 + (g16_ ^ (lm << 1));                   \
                h4_t vf = *(const h4_t*)((const __fp16*)Vs + slot_ * 8 + (lq & 1) * 4); \
                acc0[jd] = __builtin_amdgcn_mfma_f32_16x16x16f16(vf, pf0, acc0[jd], 0, 0, 0); \
                acc1[jd] = __builtin_amdgcn_mfma_f32_16x16x16f16(vf, pf1, acc1[jd], 0, 0, 0); \
            }                                                                  \
        }                                                                      \
    } while (0)

#define WRITE_O(QROW, ACC, LV)                                                 \
    do {                                                                       \
        float l_ = LV;                                                         \
        l_ += __shfl_xor(l_, 16); l_ += __shfl_xor(l_, 32);                    \
        float inv_ = 1.0f / l_;                                                \
        _Pragma("unroll")                                                      \
        for (int jd = 0; jd < 4; jd++) {                                       \
            bfx4 o_;                                                           \
            _Pragma("unroll")                                                  \
            for (int r = 0; r < 4; r++) o_[r] = (short)f2bf(ACC[jd][r] * inv_);\
            *(bfx4*)(O + (size_t)(b * SEQ + (QROW)) * D_MODEL + h * HD + jd * 16 + lq * 4) = o_; \
        }                                                                      \
    } while (0)

__global__ __launch_bounds__(256, 2)
void attn9_kernel(const unsigned short* __restrict__ Q,
                  const unsigned short* __restrict__ K,
                  const unsigned short* __restrict__ V,
                  unsigned short* __restrict__ O)
{
    __shared__ __align__(16) unsigned short Ks[256 * 64];  // [key][d] swizzled bf16, 32KB
    __shared__ __align__(16) unsigned short Vs[64 * 256];  // [d][key] swizzled f16, 32KB

    const int t = threadIdx.x;
    const int wave = t >> 6, lane = t & 63;
    const int lm = lane & 15, lq = lane >> 4;

    // XCD swizzle: nwg=1024=8*128; chunk = 8 bh x 16 j per XCD (j ascends ->
    // heavy blocks first within chunk)
    const int orig = blockIdx.x;
    const int wkid = (orig & 7) * 128 + (orig >> 3);
    const int bh = wkid >> 4;          // 0..63
    const int j  = wkid & 15;          // q supertile 0..15 (128 rows each)

    const int q0 = j * 128 + wave * 16 + lm;
    const int q1 = q0 + 64;

    const unsigned short* Qh = Q + (size_t)bh * SEQ * HD;
    const unsigned short* Kh = K + (size_t)bh * SEQ * HD;
    const unsigned short* Vh = V + (size_t)bh * HD * SEQ;  // [d][s]

    short8 bq0[2], bq1[2];
#pragma unroll
    for (int c = 0; c < 2; c++) {
        bq0[c] = *(const short8*)(Qh + (size_t)q0 * HD + c * 32 + lq * 8);
        bq1[c] = *(const short8*)(Qh + (size_t)q1 * HD + c * 32 + lq * 8);
    }

    floatx4 acc0[4] = {}, acc1[4] = {};
    float l0 = 0.f, l1 = 0.f;
    const float kA = 0.04508422002778011f;  // log2(e)/32

    const int lrow = lane >> 3, lg = lane & 7;
    const int tmin = j >> 1;

    for (int tt = 7; tt >= tmin; tt--) {
        __syncthreads();
        // K tile: 256 keys x 64 d (8 x gll16)
#pragma unroll
        for (int i = 0; i < 8; i++) {
            int rows8 = wave * 64 + i * 8;
            gll16(Kh + (size_t)(tt * 256 + rows8 + lrow) * HD + (lg ^ lrow) * 8,
                  Ks + rows8 * 64);
        }
        // V^T tile: 64 d x 256 keys (8 x gll16); 2 d-rows per gll16
#pragma unroll
        for (int i = 0; i < 8; i++) {
            int rows2 = wave * 16 + i * 2;
            int row = rows2 + (lane >> 5);
            int g = (lane & 31) ^ ((row & 15) << 1);
            gll16(Vh + (size_t)row * SEQ + tt * 256 + g * 8, Vs + rows2 * 256);
        }
        __syncthreads();

        if (tt != tmin) {
            PROCESS_SUB(1, false, tt);
            PROCESS_SUB(0, false, tt);
        } else if (j & 1) {
            PROCESS_SUB(1, true, tt);   // s = 2tt+1 = j: diagonal
            // s = j-1 fully masked: skip
        } else {
            PROCESS_SUB(1, false, tt);  // s = j+1: full
            PROCESS_SUB(0, true, tt);   // s = j: diagonal
        }
    }

    const int b = bh >> 4, h = bh & 15;
    WRITE_O(q0, acc0, l0);
    WRITE_O(q1, acc1, l1);
}

// ---------------------------------------------------------------------------
// Row 2047 is fully masked -> uniform softmax over ALL keys -> mean of V.
// ---------------------------------------------------------------------------
__global__ __launch_bounds__(256, 2)
void row2047_kernel(const unsigned short* __restrict__ V,
                    unsigned short* __restrict__ O)
{
    __shared__ float red[256];
    const int bh = blockIdx.x;
    const int b = bh >> 4, h = bh & 15;
    const int t = threadIdx.x;
    const int d = t & 63, seg = t >> 6;
    const __fp16* Vh = (const __fp16*)V + (size_t)bh * HD * SEQ + (size_t)d * SEQ + seg * 512;
    float s = 0.f;
    for (int i = 0; i < 512; i += 8) {
        h8_t v = *(const h8_t*)(Vh + i);
#pragma unroll
        for (int j = 0; j < 8; j++) s += (float)v[j];
    }
    red[t] = s;
    __syncthreads();
    if (seg == 0) {
        float tot = red[d] + red[64 + d] + red[128 + d] + red[192 + d];
        O[(size_t)(b * SEQ + 2047) * D_MODEL + h * HD + d] = f2bf(tot * (1.f / 2048.f));
    }
}

// ======================= fallback (ws < 72 MiB) kernels =====================
__global__ __launch_bounds__(256, 2)
void gemm_qkv_kernel(const float* __restrict__ A,
                     const float* __restrict__ W0,
                     const float* __restrict__ W1,
                     const float* __restrict__ W2,
                     unsigned short* __restrict__ O0,
                     unsigned short* __restrict__ O1,
                     unsigned short* __restrict__ O2)
{
    const int K = 1024;
    const float* W;
    unsigned short* Out;
    if (blockIdx.z == 0)      { W = W0; Out = O0; }
    else if (blockIdx.z == 1) { W = W1; Out = O1; }
    else                      { W = W2; Out = O2; }

    __shared__ __align__(16) unsigned short As[128 * 64];
    __shared__ __align__(16) unsigned short Bs[128 * 64];

    const int t = threadIdx.x;
    const int wave = t >> 6, lane = t & 63;
    const int lm = lane & 15, lq = lane >> 4;
    const int wrow = (wave >> 1) * 64, wcol = (wave & 1) * 64;
    const int m0 = blockIdx.x * 128, n0 = blockIdx.y * 128;

    floatx4 acc[4][4] = {};

    for (int k0 = 0; k0 < K; k0 += 64) {
        __syncthreads();
#pragma unroll
        for (int rr = 0; rr < 4; rr++) {
            int p = rr * 256 + t;
            int row = p >> 3, g = p & 7;
            const float* pa = A + (size_t)(m0 + row) * K + k0 + g * 8;
            const float* pw = W + (size_t)(n0 + row) * K + k0 + g * 8;
            floatx4 a0 = *(const floatx4*)pa, a1 = *(const floatx4*)(pa + 4);
            floatx4 w0 = *(const floatx4*)pw, w1 = *(const floatx4*)(pw + 4);
            short8 va, vb;
#pragma unroll
            for (int d = 0; d < 4; d++) {
                va[d]     = (short)f2bf(a0[d]);
                va[4 + d] = (short)f2bf(a1[d]);
                vb[d]     = (short)f2bf(w0[d]);
                vb[4 + d] = (short)f2bf(w1[d]);
            }
            int dst = row * 8 + (g ^ (row & 7));
            *(short8*)(As + dst * 8) = va;
            *(short8*)(Bs + dst * 8) = vb;
        }
        __syncthreads();

        short8 af[4][2], bf[4][2];
#pragma unroll
        for (int i = 0; i < 4; i++)
#pragma unroll
            for (int c = 0; c < 2; c++) {
                int ra = wrow + i * 16 + lm;
                int rb = wcol + i * 16 + lm;
                int g = c * 4 + lq;
                af[i][c] = *(const short8*)(As + (ra * 8 + (g ^ (ra & 7))) * 8);
                bf[i][c] = *(const short8*)(Bs + (rb * 8 + (g ^ (rb & 7))) * 8);
            }
#pragma unroll
        for (int i = 0; i < 4; i++)
#pragma unroll
            for (int j = 0; j < 4; j++)
#pragma unroll
                for (int c = 0; c < 2; c++)
                    acc[i][j] = __builtin_amdgcn_mfma_f32_16x16x32_bf16(
                        af[i][c], bf[j][c], acc[i][j], 0, 0, 0);
    }

    const int zi = blockIdx.z;
#pragma unroll
    for (int i = 0; i < 4; i++)
#pragma unroll
        for (int j = 0; j < 4; j++)
#pragma unroll
            for (int r = 0; r < 4; r++) {
                int gm = m0 + wrow + i * 16 + lq * 4 + r;
                int gn = n0 + wcol + j * 16 + lm;
                int b = gm >> 11, s = gm & 2047;
                int h = gn >> 6, d = gn & 63;
                if (zi == 2) {
                    Out[((size_t)(b * NH + h) * HD + d) * SEQ + s] = f2h(acc[i][j][r]);
                } else {
                    Out[((size_t)(b * NH + h) * SEQ + s) * HD + d] = f2bf(acc[i][j][r]);
                }
            }
}

__global__ __launch_bounds__(256, 2)
void gemm_out_kernel(const unsigned short* __restrict__ Abf,
                     const float* __restrict__ W,
                     float* __restrict__ Out)
{
    const int K = 1024;
    __shared__ __align__(16) unsigned short As[128 * 64];
    __shared__ __align__(16) unsigned short Bs[128 * 64];

    const int t = threadIdx.x;
    const int wave = t >> 6, lane = t & 63;
    const int lm = lane & 15, lq = lane >> 4;
    const int wrow = (wave >> 1) * 64, wcol = (wave & 1) * 64;
    const int m0 = blockIdx.x * 128, n0 = blockIdx.y * 128;

    floatx4 acc[4][4] = {};

    for (int k0 = 0; k0 < K; k0 += 64) {
        __syncthreads();
#pragma unroll
        for (int rr = 0; rr < 4; rr++) {
            int p = rr * 256 + t;
            int row = p >> 3, g = p & 7;
            short8 va = *(const short8*)(Abf + (size_t)(m0 + row) * K + k0 + g * 8);
            const float* pw = W + (size_t)(n0 + row) * K + k0 + g * 8;
            floatx4 w0 = *(const floatx4*)pw, w1 = *(const floatx4*)(pw + 4);
            short8 vb;
#pragma unroll
            for (int d = 0; d < 4; d++) {
                vb[d]     = (short)f2bf(w0[d]);
                vb[4 + d] = (short)f2bf(w1[d]);
            }
            int dst = row * 8 + (g ^ (row & 7));
            *(short8*)(As + dst * 8) = va;
            *(short8*)(Bs + dst * 8) = vb;
        }
        __syncthreads();

        short8 af[4][2], bf[4][2];
#pragma unroll
        for (int i = 0; i < 4; i++)
#pragma unroll
            for (int c = 0; c < 2; c++) {
                int ra = wrow + i * 16 + lm;
                int rb = wcol + i * 16 + lm;
                int g = c * 4 + lq;
                af[i][c] = *(const short8*)(As + (ra * 8 + (g ^ (ra & 7))) * 8);
                bf[i][c] = *(const short8*)(Bs + (rb * 8 + (g ^ (rb & 7))) * 8);
            }
#pragma unroll
        for (int i = 0; i < 4; i++)
#pragma unroll
            for (int j = 0; j < 4; j++)
#pragma unroll
                for (int c = 0; c < 2; c++)
                    acc[i][j] = __builtin_amdgcn_mfma_f32_16x16x32_bf16(
                        af[i][c], bf[j][c], acc[i][j], 0, 0, 0);
    }

#pragma unroll
    for (int i = 0; i < 4; i++)
#pragma unroll
        for (int j = 0; j < 4; j++)
#pragma unroll
            for (int r = 0; r < 4; r++) {
                int gm = m0 + wrow + i * 16 + lq * 4 + r;
                int gn = n0 + wcol + j * 16 + lm;
                Out[(size_t)gm * D_MODEL + gn] = acc[i][j][r];
            }
}

extern "C" void kernel_launch(void* const* d_in, const int* in_sizes, int n_in,
                              void* d_out, int out_size, void* d_ws, size_t ws_size,
                              hipStream_t stream) {
    const float* x  = (const float*)d_in[0];
    const float* wq = (const float*)d_in[1];
    const float* wk = (const float*)d_in[2];
    const float* wv = (const float*)d_in[3];
    const float* wo = (const float*)d_in[4];

    unsigned short* ws = (unsigned short*)d_ws;
    const bool fast = ws_size >= (size_t)36 * 1024 * 1024 * 2;  // 72 MiB

    if (fast) {
        unsigned short* xbf  = ws;                     // 8M elems; reused as Ob
        unsigned short* wqkv = ws + (size_t)ELEMS;     // 3M
        unsigned short* wobf = ws + (size_t)ELEMS + 3 * WELEMS;  // 1M
        unsigned short* Qb   = ws + (size_t)ELEMS + 4 * WELEMS;  // 8M
        unsigned short* Kb   = Qb + ELEMS;
        unsigned short* Vb   = Kb + ELEMS;
        unsigned short* Ob   = xbf;                    // x_bf dead after QKV GEMM

        cvt_kernel<<<6144, 256, 0, stream>>>(x, wq, wk, wv, wo, xbf, wqkv, wobf);
        gemm_qkv3_kernel<<<dim3(64, 24), 256, 0, stream>>>(xbf, wqkv, Qb, Kb, Vb);
        attn9_kernel<<<1024, 256, 0, stream>>>(Qb, Kb, Vb, Ob);
        row2047_kernel<<<BATCH * NH, 256, 0, stream>>>(Vb, Ob);
        gemm_out3_kernel<<<dim3(64, 8), 256, 0, stream>>>(Ob, wobf, (float*)d_out);
    } else {
        unsigned short* Qb = ws;
        unsigned short* Kb = Qb + ELEMS;
        unsigned short* Vb = Kb + ELEMS;
        unsigned short* Ob = Vb + ELEMS;

        gemm_qkv_kernel<<<dim3(64, 8, 3), 256, 0, stream>>>(x, wq, wk, wv, Qb, Kb, Vb);
        attn9_kernel<<<1024, 256, 0, stream>>>(Qb, Kb, Vb, Ob);
        row2047_kernel<<<BATCH * NH, 256, 0, stream>>>(Vb, Ob);
        gemm_out_kernel<<<dim3(64, 8), 256, 0, stream>>>(Ob, wo, (float*)d_out);
    }
}

// Round 9
// 272.093 us; speedup vs baseline: 1.0553x; 1.0553x over previous
//
#include <hip/hip_runtime.h>
#include <hip/hip_bf16.h>

typedef __attribute__((ext_vector_type(8))) short short8;
typedef __attribute__((ext_vector_type(4))) short bfx4;
typedef __attribute__((ext_vector_type(4))) float floatx4;
typedef __attribute__((ext_vector_type(4))) __fp16 h4_t;
typedef __attribute__((ext_vector_type(2))) __fp16 h2_t;
typedef __attribute__((ext_vector_type(8))) __fp16 h8_t;

#define BATCH 4
#define SEQ 2048
#define D_MODEL 1024
#define NH 16
#define HD 64
#define ELEMS 8388608   // B*S*D = 4*2048*1024
#define WELEMS 1048576  // 1024*1024

// fp32 -> bf16 round-to-nearest-even
__device__ __forceinline__ unsigned short f2bf(float f) {
    union { float f; unsigned u; } x; x.f = f;
    unsigned r = x.u + 0x7FFFu + ((x.u >> 16) & 1u);
    return (unsigned short)(r >> 16);
}
__device__ __forceinline__ unsigned short f2h(float f) {
    union { __fp16 h; unsigned short u; } x;
    x.h = (__fp16)f;
    return x.u;
}

#if __has_builtin(__builtin_amdgcn_exp2f)
__device__ __forceinline__ float fexp2(float x) { return __builtin_amdgcn_exp2f(x); }
#else
__device__ __forceinline__ float fexp2(float x) { return exp2f(x); }
#endif

// async global->LDS, 16B per lane; HW dest = wave-uniform base + lane*16
__device__ __forceinline__ void gll16(const void* g, const void* l) {
    __builtin_amdgcn_global_load_lds(
        (const __attribute__((address_space(1))) void*)g,
        (__attribute__((address_space(3))) void*)l,
        16, 0, 0);
}

// NOTE (session post-mortems):
//  - R1: 8-phase 256^2 counted-vmcnt GEMM port regressed. Abandoned.
//  - R2: double-buffered attn regressed: compiler drains vmcnt(0) before the
//    first ds_read of the other buffer. No source-level global_load_lds
//    pipelining.
//  - R3: 128^2 GEMM tiles > 128x256 at K=1024 (total 317->302).
//  - R4: attn7 spilled at the 128-VGPR cap. FETCH/WRITE blowup = spill sig.
//  - R5: attn8 (2 acc sets, K/V-read reuse across 2 Q-frags): 107us.
//  - R6: attn XCD swizzle WIN (107->86.5, FETCH 110->24.6MB). GEMM swizzle
//    regressed (wrong-grained resident-set arithmetic). Reverted.
//  - R7: recombined -> 268.5us best. attn8 86.7 stable.
//  - R8: attn9 KVBLK=256 regressed 86.7->125.5 from TWO implementation
//    defects, not the mechanism: (a) new V swizzle g16^(lm<<1) only spreads
//    4 banks ((lm<<1)%8 has 4 values) -> conflicts 4.46M->13.37M; (b) two
//    inlined PROCESS_SUB bodies let the scheduler interleave live ranges ->
//    VGPR 88->128 + 9MB scratch.
//  - R9 (this round): attn10 = KVBLK=256 with per-128-half layouts
//    byte-identical to attn8 (conflict gate: back to ~4.5M) and a
//    #pragma unroll 1 runtime sub-loop so code size = attn8 body
//    (VGPR gate: <=110, WRITE ~16.4MB). Either gate fails -> abandon axis.

// ---------------------------------------------------------------------------
// cvt: x (8M), wq|wk|wv (3M, concatenated), wo (1M) fp32 -> bf16
// ---------------------------------------------------------------------------
__global__ __launch_bounds__(256)
void cvt_kernel(const float* __restrict__ x,  const float* __restrict__ wq,
                const float* __restrict__ wk, const float* __restrict__ wv,
                const float* __restrict__ wo,
                unsigned short* __restrict__ xbf,
                unsigned short* __restrict__ wqkv,
                unsigned short* __restrict__ wobf)
{
    size_t idx = ((size_t)blockIdx.x * 256 + threadIdx.x) * 8;
    const float* src; unsigned short* dst; size_t off;
    if (idx < (size_t)ELEMS)                    { src = x;  dst = xbf;             off = idx; }
    else if (idx < (size_t)ELEMS + WELEMS)      { src = wq; dst = wqkv;            off = idx - ELEMS; }
    else if (idx < (size_t)ELEMS + 2 * WELEMS)  { src = wk; dst = wqkv + WELEMS;   off = idx - ELEMS - WELEMS; }
    else if (idx < (size_t)ELEMS + 3 * WELEMS)  { src = wv; dst = wqkv + 2*WELEMS; off = idx - ELEMS - 2*WELEMS; }
    else                                        { src = wo; dst = wobf;            off = idx - ELEMS - 3*WELEMS; }
    floatx4 a = *(const floatx4*)(src + off);
    floatx4 b = *(const floatx4*)(src + off + 4);
    short8 v;
#pragma unroll
    for (int d = 0; d < 4; d++) { v[d] = (short)f2bf(a[d]); v[4+d] = (short)f2bf(b[d]); }
    *(short8*)(dst + off) = v;
}

// ---------------------------------------------------------------------------
// QKV GEMM, 128x128 tile (R3/R5/R7 proven, default 2D dispatch): A=x_bf
// [8192,1024], B=wqkv_bf [3072,1024] (NT), staged via global_load_lds with
// inverse-XOR-swizzled source. BK=64, 32 KiB LDS. Grid (64,24).
// ---------------------------------------------------------------------------
__global__ __launch_bounds__(256, 2)
void gemm_qkv3_kernel(const unsigned short* __restrict__ A,
                      const unsigned short* __restrict__ B,
                      unsigned short* __restrict__ Qb,
                      unsigned short* __restrict__ Kb,
                      unsigned short* __restrict__ Vb)
{
    __shared__ __align__(16) unsigned short As[128 * 64];
    __shared__ __align__(16) unsigned short Bs[128 * 64];

    const int t = threadIdx.x;
    const int wave = t >> 6, lane = t & 63;
    const int lm = lane & 15, lq = lane >> 4;
    const int wrow = (wave >> 1) * 64, wcol = (wave & 1) * 64;
    const int m0 = blockIdx.x * 128, n0 = blockIdx.y * 128;
    const int lrow = lane >> 3, lg = lane & 7;
    const int gsw = lg ^ lrow;

    floatx4 acc[4][4] = {};

    for (int k0 = 0; k0 < 1024; k0 += 64) {
        __syncthreads();
#pragma unroll
        for (int i = 0; i < 4; i++) {
            int rows8 = wave * 32 + i * 8;
            gll16(A + (size_t)(m0 + rows8 + lrow) * 1024 + k0 + gsw * 8, As + rows8 * 64);
            gll16(B + (size_t)(n0 + rows8 + lrow) * 1024 + k0 + gsw * 8, Bs + rows8 * 64);
        }
        __syncthreads();

#pragma unroll
        for (int c = 0; c < 2; c++) {
            short8 af[4], bfr[4];
#pragma unroll
            for (int i = 0; i < 4; i++) {
                int ra = wrow + i * 16 + lm;
                int g = c * 4 + lq;
                af[i] = *(const short8*)(As + (ra * 8 + (g ^ (ra & 7))) * 8);
            }
#pragma unroll
            for (int j = 0; j < 4; j++) {
                int rb = wcol + j * 16 + lm;
                int g = c * 4 + lq;
                bfr[j] = *(const short8*)(Bs + (rb * 8 + (g ^ (rb & 7))) * 8);
            }
#pragma unroll
            for (int i = 0; i < 4; i++)
#pragma unroll
                for (int j = 0; j < 4; j++)
                    acc[i][j] = __builtin_amdgcn_mfma_f32_16x16x32_bf16(
                        af[i], bfr[j], acc[i][j], 0, 0, 0);
        }
    }

    const int z = n0 >> 10;   // 0=Q 1=K 2=V, uniform per block
#pragma unroll
    for (int i = 0; i < 4; i++)
#pragma unroll
        for (int j = 0; j < 4; j++)
#pragma unroll
            for (int r = 0; r < 4; r++) {
                int gm = m0 + wrow + i * 16 + lq * 4 + r;
                int gn = n0 + wcol + j * 16 + lm;
                int nl = gn & 1023, h = nl >> 6, d = nl & 63;
                int b = gm >> 11, s = gm & 2047;
                float v = acc[i][j][r];
                size_t bh = (size_t)(b * NH + h);
                if (z == 0)      Qb[(bh * SEQ + s) * HD + d] = f2bf(v);
                else if (z == 1) Kb[(bh * SEQ + s) * HD + d] = f2bf(v);
                else             Vb[(bh * HD + d) * SEQ + s] = f2h(v);
            }
}

// ---------------------------------------------------------------------------
// Output projection, 128x128 tile (R3/R5/R7 proven, default 2D dispatch):
// A=Ob bf16 [8192,1024], B=wo_bf [1024,1024] -> fp32. Grid (64,8).
// ---------------------------------------------------------------------------
__global__ __launch_bounds__(256, 2)
void gemm_out3_kernel(const unsigned short* __restrict__ A,
                      const unsigned short* __restrict__ B,
                      float* __restrict__ Out)
{
    __shared__ __align__(16) unsigned short As[128 * 64];
    __shared__ __align__(16) unsigned short Bs[128 * 64];

    const int t = threadIdx.x;
    const int wave = t >> 6, lane = t & 63;
    const int lm = lane & 15, lq = lane >> 4;
    const int wrow = (wave >> 1) * 64, wcol = (wave & 1) * 64;
    const int m0 = blockIdx.x * 128, n0 = blockIdx.y * 128;
    const int lrow = lane >> 3, lg = lane & 7;
    const int gsw = lg ^ lrow;

    floatx4 acc[4][4] = {};

    for (int k0 = 0; k0 < 1024; k0 += 64) {
        __syncthreads();
#pragma unroll
        for (int i = 0; i < 4; i++) {
            int rows8 = wave * 32 + i * 8;
            gll16(A + (size_t)(m0 + rows8 + lrow) * 1024 + k0 + gsw * 8, As + rows8 * 64);
            gll16(B + (size_t)(n0 + rows8 + lrow) * 1024 + k0 + gsw * 8, Bs + rows8 * 64);
        }
        __syncthreads();

#pragma unroll
        for (int c = 0; c < 2; c++) {
            short8 af[4], bfr[4];
#pragma unroll
            for (int i = 0; i < 4; i++) {
                int ra = wrow + i * 16 + lm;
                int g = c * 4 + lq;
                af[i] = *(const short8*)(As + (ra * 8 + (g ^ (ra & 7))) * 8);
            }
#pragma unroll
            for (int j = 0; j < 4; j++) {
                int rb = wcol + j * 16 + lm;
                int g = c * 4 + lq;
                bfr[j] = *(const short8*)(Bs + (rb * 8 + (g ^ (rb & 7))) * 8);
            }
#pragma unroll
            for (int i = 0; i < 4; i++)
#pragma unroll
                for (int j = 0; j < 4; j++)
                    acc[i][j] = __builtin_amdgcn_mfma_f32_16x16x32_bf16(
                        af[i], bfr[j], acc[i][j], 0, 0, 0);
        }
    }

#pragma unroll
    for (int i = 0; i < 4; i++)
#pragma unroll
        for (int j = 0; j < 4; j++)
#pragma unroll
            for (int r = 0; r < 4; r++) {
                int gm = m0 + wrow + i * 16 + lq * 4 + r;
                int gn = n0 + wcol + j * 16 + lm;
                Out[(size_t)gm * D_MODEL + gn] = acc[i][j][r];
            }
}

// ---------------------------------------------------------------------------
// Flash attention v10: KVBLK=256 staged as TWO independent 128-key halves,
// each byte-identical to attn8's proven K/V LDS layout (fixes R8's broken
// 256-wide V swizzle -> conflicts back to attn8 levels). The two sub-tiles
// are processed by a '#pragma unroll 1' RUNTIME loop over one PROCESS body
// (fixes R8's code-doubling VGPR blowup). Drain events halve vs attn8
// (72 vs 136 per bh) at attn8's register footprint.
// Sub s at tile tt = key-tile kt=2tt+s; mask only when kt==j; odd-j blocks
// skip the dead s=0 sub-tile at tt=tmin.
// 2 Q-frags/wave + XCD swizzle as attn8 (R5/R6 proven). LDS 64KB.
// Q,K bf16 [b,h,s,d]; V f16 [b,h,d,s]; O bf16 [b,s,1024].
// Row 2047 (l=0 -> NaN) overwritten by row2047_kernel afterwards.
// ---------------------------------------------------------------------------
#define PROCESS_SUB(KSB, VSB, KT, DOMASK)                                      \
    do {                                                                       \
        _Pragma("unroll")                                                      \
        for (int jt = 0; jt < 8; jt++) {                                       \
            floatx4 sc0 = {}, sc1 = {};                                        \
            _Pragma("unroll")                                                  \
            for (int c = 0; c < 2; c++) {                                      \
                int row_ = jt * 16 + lm;                                       \
                int g_ = c * 4 + lq;                                           \
                short8 kf = *(const short8*)((KSB) + (row_ * 8 + (g_ ^ (row_ & 7))) * 8); \
                sc0 = __builtin_amdgcn_mfma_f32_16x16x32_bf16(kf, bq0[c], sc0, 0, 0, 0); \
                sc1 = __builtin_amdgcn_mfma_f32_16x16x32_bf16(kf, bq1[c], sc1, 0, 0, 0); \
            }                                                                  \
            if (DOMASK) {                                                      \
                _Pragma("unroll")                                              \
                for (int r = 0; r < 4; r++) {                                  \
                    int kj = (KT) * 128 + jt * 16 + lq * 4 + r;                \
                    if (!(kj > q0)) sc0[r] = -3.2e10f;                         \
                    if (!(kj > q1)) sc1[r] = -3.2e10f;                         \
                }                                                              \
            }                                                                  \
            float p00 = fexp2(sc0[0] * kA), p01 = fexp2(sc0[1] * kA);          \
            float p02 = fexp2(sc0[2] * kA), p03 = fexp2(sc0[3] * kA);          \
            float p10 = fexp2(sc1[0] * kA), p11 = fexp2(sc1[1] * kA);          \
            float p12 = fexp2(sc1[2] * kA), p13 = fexp2(sc1[3] * kA);          \
            l0 += (p00 + p01) + (p02 + p03);                                   \
            l1 += (p10 + p11) + (p12 + p13);                                   \
            h2_t a0_ = __builtin_amdgcn_cvt_pkrtz(p00, p01);                   \
            h2_t b0_ = __builtin_amdgcn_cvt_pkrtz(p02, p03);                   \
            h2_t a1_ = __builtin_amdgcn_cvt_pkrtz(p10, p11);                   \
            h2_t b1_ = __builtin_amdgcn_cvt_pkrtz(p12, p13);                   \
            h4_t pf0, pf1;                                                     \
            pf0[0] = a0_[0]; pf0[1] = a0_[1]; pf0[2] = b0_[0]; pf0[3] = b0_[1];\
            pf1[0] = a1_[0]; pf1[1] = a1_[1]; pf1[2] = b1_[0]; pf1[3] = b1_[1];\
            _Pragma("unroll")                                                  \
            for (int jd = 0; jd < 4; jd++) {                                   \
                int rowv_ = jd * 16 + lm;                                      \
                int g16_ = jt * 2 + (lq >> 1);                                 \
                int slot_ = rowv_ * 16 + (g16_ ^ lm);                          \
                h4_t vf = *(const h4_t*)((VSB) + slot_ * 8 + (lq & 1) * 4);    \
                acc0[jd] = __builtin_amdgcn_mfma_f32_16x16x16f16(vf, pf0, acc0[jd], 0, 0, 0); \
                acc1[jd] = __builtin_amdgcn_mfma_f32_16x16x16f16(vf, pf1, acc1[jd], 0, 0, 0); \
            }                                                                  \
        }                                                                      \
    } while (0)

#define WRITE_O(QROW, ACC, LV)                                                 \
    do {                                                                       \
        float l_ = LV;                                                         \
        l_ += __shfl_xor(l_, 16); l_ += __shfl_xor(l_, 32);                    \
        float inv_ = 1.0f / l_;                                                \
        _Pragma("unroll")                                                      \
        for (int jd = 0; jd < 4; jd++) {                                       \
            bfx4 o_;                                                           \
            _Pragma("unroll")                                                  \
            for (int r = 0; r < 4; r++) o_[r] = (short)f2bf(ACC[jd][r] * inv_);\
            *(bfx4*)(O + (size_t)(b * SEQ + (QROW)) * D_MODEL + h * HD + jd * 16 + lq * 4) = o_; \
        }                                                                      \
    } while (0)

__global__ __launch_bounds__(256, 2)
void attn10_kernel(const unsigned short* __restrict__ Q,
                   const unsigned short* __restrict__ K,
                   const unsigned short* __restrict__ V,
                   unsigned short* __restrict__ O)
{
    // two independent 128-key halves, each with attn8's exact layout
    __shared__ __align__(16) unsigned short Ks[2 * 128 * 64];  // 32KB bf16
    __shared__ __align__(16) unsigned short Vs[2 * 64 * 128];  // 32KB f16

    const int t = threadIdx.x;
    const int wave = t >> 6, lane = t & 63;
    const int lm = lane & 15, lq = lane >> 4;

    // XCD swizzle: nwg=1024=8*128; chunk = 8 bh x 16 j per XCD
    const int orig = blockIdx.x;
    const int wkid = (orig & 7) * 128 + (orig >> 3);
    const int bh = wkid >> 4;          // 0..63
    const int j  = wkid & 15;          // q supertile 0..15 (128 rows each)

    const int q0 = j * 128 + wave * 16 + lm;
    const int q1 = q0 + 64;

    const unsigned short* Qh = Q + (size_t)bh * SEQ * HD;
    const unsigned short* Kh = K + (size_t)bh * SEQ * HD;
    const unsigned short* Vh = V + (size_t)bh * HD * SEQ;  // [d][s]

    short8 bq0[2], bq1[2];
#pragma unroll
    for (int c = 0; c < 2; c++) {
        bq0[c] = *(const short8*)(Qh + (size_t)q0 * HD + c * 32 + lq * 8);
        bq1[c] = *(const short8*)(Qh + (size_t)q1 * HD + c * 32 + lq * 8);
    }

    floatx4 acc0[4] = {}, acc1[4] = {};
    float l0 = 0.f, l1 = 0.f;
    const float kA = 0.04508422002778011f;  // log2(e)/32

    const int lrow = lane >> 3, lg = lane & 7;
    const int tmin = j >> 1;

    for (int tt = 7; tt >= tmin; tt--) {
        __syncthreads();
        // stage both halves: K 2x(128 keys x 64 d), V^T 2x(64 d x 128 keys),
        // each half byte-identical to attn8's staging
#pragma unroll
        for (int h2 = 0; h2 < 2; h2++) {
#pragma unroll
            for (int i = 0; i < 4; i++) {
                int rows8 = wave * 32 + i * 8;
                gll16(Kh + (size_t)(tt * 256 + h2 * 128 + rows8 + lrow) * HD + (lg ^ lrow) * 8,
                      Ks + h2 * (128 * 64) + rows8 * 64);
            }
#pragma unroll
            for (int i = 0; i < 4; i++) {
                int rows4 = wave * 16 + i * 4;
                int row = rows4 + (lane >> 4);
                int g = (lane & 15) ^ (row & 15);
                gll16(Vh + (size_t)row * SEQ + tt * 256 + h2 * 128 + g * 8,
                      Vs + h2 * (64 * 128) + rows4 * 128);
            }
        }
        __syncthreads();

        // odd-j blocks skip the dead s=0 sub-tile at tt==tmin
        const int s_lo = (tt == tmin && (j & 1)) ? 1 : 0;
#pragma unroll 1
        for (int s = 1; s >= s_lo; s--) {
            const unsigned short* Ksb = Ks + s * (128 * 64);
            const __fp16* Vsb = (const __fp16*)(Vs + s * (64 * 128));
            const bool domask = (tt == tmin) && (s == (j & 1));
            const int kt = tt * 2 + s;
            PROCESS_SUB(Ksb, Vsb, kt, domask);
        }
    }

    const int b = bh >> 4, h = bh & 15;
    WRITE_O(q0, acc0, l0);
    WRITE_O(q1, acc1, l1);
}

// ---------------------------------------------------------------------------
// Row 2047 is fully masked -> uniform softmax over ALL keys -> mean of V.
// ---------------------------------------------------------------------------
__global__ __launch_bounds__(256, 2)
void row2047_kernel(const unsigned short* __restrict__ V,
                    unsigned short* __restrict__ O)
{
    __shared__ float red[256];
    const int bh = blockIdx.x;
    const int b = bh >> 4, h = bh & 15;
    const int t = threadIdx.x;
    const int d = t & 63, seg = t >> 6;
    const __fp16* Vh = (const __fp16*)V + (size_t)bh * HD * SEQ + (size_t)d * SEQ + seg * 512;
    float s = 0.f;
    for (int i = 0; i < 512; i += 8) {
        h8_t v = *(const h8_t*)(Vh + i);
#pragma unroll
        for (int j = 0; j < 8; j++) s += (float)v[j];
    }
    red[t] = s;
    __syncthreads();
    if (seg == 0) {
        float tot = red[d] + red[64 + d] + red[128 + d] + red[192 + d];
        O[(size_t)(b * SEQ + 2047) * D_MODEL + h * HD + d] = f2bf(tot * (1.f / 2048.f));
    }
}

// ======================= fallback (ws < 72 MiB) kernels =====================
__global__ __launch_bounds__(256, 2)
void gemm_qkv_kernel(const float* __restrict__ A,
                     const float* __restrict__ W0,
                     const float* __restrict__ W1,
                     const float* __restrict__ W2,
                     unsigned short* __restrict__ O0,
                     unsigned short* __restrict__ O1,
                     unsigned short* __restrict__ O2)
{
    const int K = 1024;
    const float* W;
    unsigned short* Out;
    if (blockIdx.z == 0)      { W = W0; Out = O0; }
    else if (blockIdx.z == 1) { W = W1; Out = O1; }
    else                      { W = W2; Out = O2; }

    __shared__ __align__(16) unsigned short As[128 * 64];
    __shared__ __align__(16) unsigned short Bs[128 * 64];

    const int t = threadIdx.x;
    const int wave = t >> 6, lane = t & 63;
    const int lm = lane & 15, lq = lane >> 4;
    const int wrow = (wave >> 1) * 64, wcol = (wave & 1) * 64;
    const int m0 = blockIdx.x * 128, n0 = blockIdx.y * 128;

    floatx4 acc[4][4] = {};

    for (int k0 = 0; k0 < K; k0 += 64) {
        __syncthreads();
#pragma unroll
        for (int rr = 0; rr < 4; rr++) {
            int p = rr * 256 + t;
            int row = p >> 3, g = p & 7;
            const float* pa = A + (size_t)(m0 + row) * K + k0 + g * 8;
            const float* pw = W + (size_t)(n0 + row) * K + k0 + g * 8;
            floatx4 a0 = *(const floatx4*)pa, a1 = *(const floatx4*)(pa + 4);
            floatx4 w0 = *(const floatx4*)pw, w1 = *(const floatx4*)(pw + 4);
            short8 va, vb;
#pragma unroll
            for (int d = 0; d < 4; d++) {
                va[d]     = (short)f2bf(a0[d]);
                va[4 + d] = (short)f2bf(a1[d]);
                vb[d]     = (short)f2bf(w0[d]);
                vb[4 + d] = (short)f2bf(w1[d]);
            }
            int dst = row * 8 + (g ^ (row & 7));
            *(short8*)(As + dst * 8) = va;
            *(short8*)(Bs + dst * 8) = vb;
        }
        __syncthreads();

        short8 af[4][2], bf[4][2];
#pragma unroll
        for (int i = 0; i < 4; i++)
#pragma unroll
            for (int c = 0; c < 2; c++) {
                int ra = wrow + i * 16 + lm;
                int rb = wcol + i * 16 + lm;
                int g = c * 4 + lq;
                af[i][c] = *(const short8*)(As + (ra * 8 + (g ^ (ra & 7))) * 8);
                bf[i][c] = *(const short8*)(Bs + (rb * 8 + (g ^ (rb & 7))) * 8);
            }
#pragma unroll
        for (int i = 0; i < 4; i++)
#pragma unroll
            for (int j = 0; j < 4; j++)
#pragma unroll
                for (int c = 0; c < 2; c++)
                    acc[i][j] = __builtin_amdgcn_mfma_f32_16x16x32_bf16(
                        af[i][c], bf[j][c], acc[i][j], 0, 0, 0);
    }

    const int zi = blockIdx.z;
#pragma unroll
    for (int i = 0; i < 4; i++)
#pragma unroll
        for (int j = 0; j < 4; j++)
#pragma unroll
            for (int r = 0; r < 4; r++) {
                int gm = m0 + wrow + i * 16 + lq * 4 + r;
                int gn = n0 + wcol + j * 16 + lm;
                int b = gm >> 11, s = gm & 2047;
                int h = gn >> 6, d = gn & 63;
                if (zi == 2) {
                    Out[((size_t)(b * NH + h) * HD + d) * SEQ + s] = f2h(acc[i][j][r]);
                } else {
                    Out[((size_t)(b * NH + h) * SEQ + s) * HD + d] = f2bf(acc[i][j][r]);
                }
            }
}

__global__ __launch_bounds__(256, 2)
void gemm_out_kernel(const unsigned short* __restrict__ Abf,
                     const float* __restrict__ W,
                     float* __restrict__ Out)
{
    const int K = 1024;
    __shared__ __align__(16) unsigned short As[128 * 64];
    __shared__ __align__(16) unsigned short Bs[128 * 64];

    const int t = threadIdx.x;
    const int wave = t >> 6, lane = t & 63;
    const int lm = lane & 15, lq = lane >> 4;
    const int wrow = (wave >> 1) * 64, wcol = (wave & 1) * 64;
    const int m0 = blockIdx.x * 128, n0 = blockIdx.y * 128;

    floatx4 acc[4][4] = {};

    for (int k0 = 0; k0 < K; k0 += 64) {
        __syncthreads();
#pragma unroll
        for (int rr = 0; rr < 4; rr++) {
            int p = rr * 256 + t;
            int row = p >> 3, g = p & 7;
            short8 va = *(const short8*)(Abf + (size_t)(m0 + row) * K + k0 + g * 8);
            const float* pw = W + (size_t)(n0 + row) * K + k0 + g * 8;
            floatx4 w0 = *(const floatx4*)pw, w1 = *(const floatx4*)(pw + 4);
            short8 vb;
#pragma unroll
            for (int d = 0; d < 4; d++) {
                vb[d]     = (short)f2bf(w0[d]);
                vb[4 + d] = (short)f2bf(w1[d]);
            }
            int dst = row * 8 + (g ^ (row & 7));
            *(short8*)(As + dst * 8) = va;
            *(short8*)(Bs + dst * 8) = vb;
        }
        __syncthreads();

        short8 af[4][2], bf[4][2];
#pragma unroll
        for (int i = 0; i < 4; i++)
#pragma unroll
            for (int c = 0; c < 2; c++) {
                int ra = wrow + i * 16 + lm;
                int rb = wcol + i * 16 + lm;
                int g = c * 4 + lq;
                af[i][c] = *(const short8*)(As + (ra * 8 + (g ^ (ra & 7))) * 8);
                bf[i][c] = *(const short8*)(Bs + (rb * 8 + (g ^ (rb & 7))) * 8);
            }
#pragma unroll
        for (int i = 0; i < 4; i++)
#pragma unroll
            for (int j = 0; j < 4; j++)
#pragma unroll
                for (int c = 0; c < 2; c++)
                    acc[i][j] = __builtin_amdgcn_mfma_f32_16x16x32_bf16(
                        af[i][c], bf[j][c], acc[i][j], 0, 0, 0);
    }

#pragma unroll
    for (int i = 0; i < 4; i++)
#pragma unroll
        for (int j = 0; j < 4; j++)
#pragma unroll
            for (int r = 0; r < 4; r++) {
                int gm = m0 + wrow + i * 16 + lq * 4 + r;
                int gn = n0 + wcol + j * 16 + lm;
                Out[(size_t)gm * D_MODEL + gn] = acc[i][j][r];
            }
}

extern "C" void kernel_launch(void* const* d_in, const int* in_sizes, int n_in,
                              void* d_out, int out_size, void* d_ws, size_t ws_size,
                              hipStream_t stream) {
    const float* x  = (const float*)d_in[0];
    const float* wq = (const float*)d_in[1];
    const float* wk = (const float*)d_in[2];
    const float* wv = (const float*)d_in[3];
    const float* wo = (const float*)d_in[4];

    unsigned short* ws = (unsigned short*)d_ws;
    const bool fast = ws_size >= (size_t)36 * 1024 * 1024 * 2;  // 72 MiB

    if (fast) {
        unsigned short* xbf  = ws;                     // 8M elems; reused as Ob
        unsigned short* wqkv = ws + (size_t)ELEMS;     // 3M
        unsigned short* wobf = ws + (size_t)ELEMS + 3 * WELEMS;  // 1M
        unsigned short* Qb   = ws + (size_t)ELEMS + 4 * WELEMS;  // 8M
        unsigned short* Kb   = Qb + ELEMS;
        unsigned short* Vb   = Kb + ELEMS;
        unsigned short* Ob   = xbf;                    // x_bf dead after QKV GEMM

        cvt_kernel<<<6144, 256, 0, stream>>>(x, wq, wk, wv, wo, xbf, wqkv, wobf);
        gemm_qkv3_kernel<<<dim3(64, 24), 256, 0, stream>>>(xbf, wqkv, Qb, Kb, Vb);
        attn10_kernel<<<1024, 256, 0, stream>>>(Qb, Kb, Vb, Ob);
        row2047_kernel<<<BATCH * NH, 256, 0, stream>>>(Vb, Ob);
        gemm_out3_kernel<<<dim3(64, 8), 256, 0, stream>>>(Ob, wobf, (float*)d_out);
    } else {
        unsigned short* Qb = ws;
        unsigned short* Kb = Qb + ELEMS;
        unsigned short* Vb = Kb + ELEMS;
        unsigned short* Ob = Vb + ELEMS;

        gemm_qkv_kernel<<<dim3(64, 8, 3), 256, 0, stream>>>(x, wq, wk, wv, Qb, Kb, Vb);
        attn10_kernel<<<1024, 256, 0, stream>>>(Qb, Kb, Vb, Ob);
        row2047_kernel<<<BATCH * NH, 256, 0, stream>>>(Vb, Ob);
        gemm_out_kernel<<<dim3(64, 8), 256, 0, stream>>>(Ob, wo, (float*)d_out);
    }
}

// Round 10
// 270.123 us; speedup vs baseline: 1.0630x; 1.0073x over previous
//
#include <hip/hip_runtime.h>
#include <hip/hip_bf16.h>

typedef __attribute__((ext_vector_type(8))) short short8;
typedef __attribute__((ext_vector_type(4))) short bfx4;
typedef __attribute__((ext_vector_type(4))) float floatx4;
typedef __attribute__((ext_vector_type(4))) __fp16 h4_t;
typedef __attribute__((ext_vector_type(2))) __fp16 h2_t;
typedef __attribute__((ext_vector_type(8))) __fp16 h8_t;

#define BATCH 4
#define SEQ 2048
#define D_MODEL 1024
#define NH 16
#define HD 64
#define ELEMS 8388608   // B*S*D = 4*2048*1024
#define WELEMS 1048576  // 1024*1024

// fp32 -> bf16 round-to-nearest-even
__device__ __forceinline__ unsigned short f2bf(float f) {
    union { float f; unsigned u; } x; x.f = f;
    unsigned r = x.u + 0x7FFFu + ((x.u >> 16) & 1u);
    return (unsigned short)(r >> 16);
}
__device__ __forceinline__ unsigned short f2h(float f) {
    union { __fp16 h; unsigned short u; } x;
    x.h = (__fp16)f;
    return x.u;
}

#if __has_builtin(__builtin_amdgcn_exp2f)
__device__ __forceinline__ float fexp2(float x) { return __builtin_amdgcn_exp2f(x); }
#else
__device__ __forceinline__ float fexp2(float x) { return exp2f(x); }
#endif

// async global->LDS, 16B per lane; HW dest = wave-uniform base + lane*16
__device__ __forceinline__ void gll16(const void* g, const void* l) {
    __builtin_amdgcn_global_load_lds(
        (const __attribute__((address_space(1))) void*)g,
        (__attribute__((address_space(3))) void*)l,
        16, 0, 0);
}

// NOTE (session post-mortems):
//  - R1: 8-phase 256^2 counted-vmcnt GEMM port regressed. Abandoned.
//  - R2: dbuf attn with __syncthreads regressed (implicit vmcnt(0) +
//    runtime-indexed buffer kills alias analysis). Root cause fix never
//    tried until R10.
//  - R3: 128^2 GEMM tiles > 128x256 at K=1024.
//  - R4: attn7 spilled at the 128-VGPR cap. FETCH/WRITE blowup = spill sig.
//  - R5: attn8 (2 acc sets, K/V-read reuse across 2 Q-frags): 107us.
//  - R6: attn XCD swizzle WIN (107->86.5, FETCH 110->24.6MB). GEMM swizzle
//    regressed. Reverted.
//  - R7: recombined -> 268.5us best. attn8 86.7 stable.
//  - R8: attn9 KVBLK=256 regressed on two impl defects (bad V swizzle ->
//    13.4M conflicts; double-inlined body -> VGPR 128 + spill).
//  - R9: attn10 fixed both defects (gates passed: 96 VGPR, 4.46M conflicts)
//    -> dur 87.9 = attn8. NULL: per-tile stall scales with BYTES staged,
//    not event count. KVBLK axis dead.
//  - R10 (this round): attn11 = attn8 + true double-buffer done the
//    T3-minimum way: DISTINCT static LDS objects (KsA/VsA/KsB/VsB, each
//    byte-identical to attn8's layout), compile-time buffer selection via
//    manual 2-phase unroll, raw s_barrier + explicit asm vmcnt(0) AFTER
//    compute (never before), sched_barrier(0) pin. No __syncthreads in the
//    loop. Stage latency streams under compute. Gates: VGPR<=112,
//    WRITE ~16.4MB, conflicts ~4.46M. Failure A (dur flat ~87): source-level
//    async impossible -> settle at R7. Failure B (spill): revert.

// ---------------------------------------------------------------------------
// cvt: x (8M), wq|wk|wv (3M, concatenated), wo (1M) fp32 -> bf16
// ---------------------------------------------------------------------------
__global__ __launch_bounds__(256)
void cvt_kernel(const float* __restrict__ x,  const float* __restrict__ wq,
                const float* __restrict__ wk, const float* __restrict__ wv,
                const float* __restrict__ wo,
                unsigned short* __restrict__ xbf,
                unsigned short* __restrict__ wqkv,
                unsigned short* __restrict__ wobf)
{
    size_t idx = ((size_t)blockIdx.x * 256 + threadIdx.x) * 8;
    const float* src; unsigned short* dst; size_t off;
    if (idx < (size_t)ELEMS)                    { src = x;  dst = xbf;             off = idx; }
    else if (idx < (size_t)ELEMS + WELEMS)      { src = wq; dst = wqkv;            off = idx - ELEMS; }
    else if (idx < (size_t)ELEMS + 2 * WELEMS)  { src = wk; dst = wqkv + WELEMS;   off = idx - ELEMS - WELEMS; }
    else if (idx < (size_t)ELEMS + 3 * WELEMS)  { src = wv; dst = wqkv + 2*WELEMS; off = idx - ELEMS - 2*WELEMS; }
    else                                        { src = wo; dst = wobf;            off = idx - ELEMS - 3*WELEMS; }
    floatx4 a = *(const floatx4*)(src + off);
    floatx4 b = *(const floatx4*)(src + off + 4);
    short8 v;
#pragma unroll
    for (int d = 0; d < 4; d++) { v[d] = (short)f2bf(a[d]); v[4+d] = (short)f2bf(b[d]); }
    *(short8*)(dst + off) = v;
}

// ---------------------------------------------------------------------------
// QKV GEMM, 128x128 tile (R3/R5/R7 proven, default 2D dispatch): A=x_bf
// [8192,1024], B=wqkv_bf [3072,1024] (NT), staged via global_load_lds with
// inverse-XOR-swizzled source. BK=64, 32 KiB LDS. Grid (64,24).
// ---------------------------------------------------------------------------
__global__ __launch_bounds__(256, 2)
void gemm_qkv3_kernel(const unsigned short* __restrict__ A,
                      const unsigned short* __restrict__ B,
                      unsigned short* __restrict__ Qb,
                      unsigned short* __restrict__ Kb,
                      unsigned short* __restrict__ Vb)
{
    __shared__ __align__(16) unsigned short As[128 * 64];
    __shared__ __align__(16) unsigned short Bs[128 * 64];

    const int t = threadIdx.x;
    const int wave = t >> 6, lane = t & 63;
    const int lm = lane & 15, lq = lane >> 4;
    const int wrow = (wave >> 1) * 64, wcol = (wave & 1) * 64;
    const int m0 = blockIdx.x * 128, n0 = blockIdx.y * 128;
    const int lrow = lane >> 3, lg = lane & 7;
    const int gsw = lg ^ lrow;

    floatx4 acc[4][4] = {};

    for (int k0 = 0; k0 < 1024; k0 += 64) {
        __syncthreads();
#pragma unroll
        for (int i = 0; i < 4; i++) {
            int rows8 = wave * 32 + i * 8;
            gll16(A + (size_t)(m0 + rows8 + lrow) * 1024 + k0 + gsw * 8, As + rows8 * 64);
            gll16(B + (size_t)(n0 + rows8 + lrow) * 1024 + k0 + gsw * 8, Bs + rows8 * 64);
        }
        __syncthreads();

#pragma unroll
        for (int c = 0; c < 2; c++) {
            short8 af[4], bfr[4];
#pragma unroll
            for (int i = 0; i < 4; i++) {
                int ra = wrow + i * 16 + lm;
                int g = c * 4 + lq;
                af[i] = *(const short8*)(As + (ra * 8 + (g ^ (ra & 7))) * 8);
            }
#pragma unroll
            for (int j = 0; j < 4; j++) {
                int rb = wcol + j * 16 + lm;
                int g = c * 4 + lq;
                bfr[j] = *(const short8*)(Bs + (rb * 8 + (g ^ (rb & 7))) * 8);
            }
#pragma unroll
            for (int i = 0; i < 4; i++)
#pragma unroll
                for (int j = 0; j < 4; j++)
                    acc[i][j] = __builtin_amdgcn_mfma_f32_16x16x32_bf16(
                        af[i], bfr[j], acc[i][j], 0, 0, 0);
        }
    }

    const int z = n0 >> 10;   // 0=Q 1=K 2=V, uniform per block
#pragma unroll
    for (int i = 0; i < 4; i++)
#pragma unroll
        for (int j = 0; j < 4; j++)
#pragma unroll
            for (int r = 0; r < 4; r++) {
                int gm = m0 + wrow + i * 16 + lq * 4 + r;
                int gn = n0 + wcol + j * 16 + lm;
                int nl = gn & 1023, h = nl >> 6, d = nl & 63;
                int b = gm >> 11, s = gm & 2047;
                float v = acc[i][j][r];
                size_t bh = (size_t)(b * NH + h);
                if (z == 0)      Qb[(bh * SEQ + s) * HD + d] = f2bf(v);
                else if (z == 1) Kb[(bh * SEQ + s) * HD + d] = f2bf(v);
                else             Vb[(bh * HD + d) * SEQ + s] = f2h(v);
            }
}

// ---------------------------------------------------------------------------
// Output projection, 128x128 tile (R3/R5/R7 proven, default 2D dispatch):
// A=Ob bf16 [8192,1024], B=wo_bf [1024,1024] -> fp32. Grid (64,8).
// ---------------------------------------------------------------------------
__global__ __launch_bounds__(256, 2)
void gemm_out3_kernel(const unsigned short* __restrict__ A,
                      const unsigned short* __restrict__ B,
                      float* __restrict__ Out)
{
    __shared__ __align__(16) unsigned short As[128 * 64];
    __shared__ __align__(16) unsigned short Bs[128 * 64];

    const int t = threadIdx.x;
    const int wave = t >> 6, lane = t & 63;
    const int lm = lane & 15, lq = lane >> 4;
    const int wrow = (wave >> 1) * 64, wcol = (wave & 1) * 64;
    const int m0 = blockIdx.x * 128, n0 = blockIdx.y * 128;
    const int lrow = lane >> 3, lg = lane & 7;
    const int gsw = lg ^ lrow;

    floatx4 acc[4][4] = {};

    for (int k0 = 0; k0 < 1024; k0 += 64) {
        __syncthreads();
#pragma unroll
        for (int i = 0; i < 4; i++) {
            int rows8 = wave * 32 + i * 8;
            gll16(A + (size_t)(m0 + rows8 + lrow) * 1024 + k0 + gsw * 8, As + rows8 * 64);
            gll16(B + (size_t)(n0 + rows8 + lrow) * 1024 + k0 + gsw * 8, Bs + rows8 * 64);
        }
        __syncthreads();

#pragma unroll
        for (int c = 0; c < 2; c++) {
            short8 af[4], bfr[4];
#pragma unroll
            for (int i = 0; i < 4; i++) {
                int ra = wrow + i * 16 + lm;
                int g = c * 4 + lq;
                af[i] = *(const short8*)(As + (ra * 8 + (g ^ (ra & 7))) * 8);
            }
#pragma unroll
            for (int j = 0; j < 4; j++) {
                int rb = wcol + j * 16 + lm;
                int g = c * 4 + lq;
                bfr[j] = *(const short8*)(Bs + (rb * 8 + (g ^ (rb & 7))) * 8);
            }
#pragma unroll
            for (int i = 0; i < 4; i++)
#pragma unroll
                for (int j = 0; j < 4; j++)
                    acc[i][j] = __builtin_amdgcn_mfma_f32_16x16x32_bf16(
                        af[i], bfr[j], acc[i][j], 0, 0, 0);
        }
    }

#pragma unroll
    for (int i = 0; i < 4; i++)
#pragma unroll
        for (int j = 0; j < 4; j++)
#pragma unroll
            for (int r = 0; r < 4; r++) {
                int gm = m0 + wrow + i * 16 + lq * 4 + r;
                int gn = n0 + wcol + j * 16 + lm;
                Out[(size_t)gm * D_MODEL + gn] = acc[i][j][r];
            }
}

// ---------------------------------------------------------------------------
// Flash attention v11: attn8 (R5/R6 proven: 2 Q-frags/wave, XCD swizzle,
// KVBLK=128) + TRUE double-buffer via the T3-minimum recipe:
//   - 4 DISTINCT static LDS arrays (KsA/VsA/KsB/VsB), each byte-identical
//     to attn8's proven layout -> alias analysis sees disjoint objects,
//     no conservative vmcnt insertion before the compute's ds_reads.
//   - manual 2-phase unroll so buffer choice is COMPILE-TIME per phase.
//   - per tile: STAGE(other buf) -> PROCESS(cur) -> asm vmcnt(0) -> raw
//     s_barrier -> sched_barrier(0). vmcnt lands AFTER compute (stage
//     latency hidden); no __syncthreads (whose implicit vmcnt(0) killed R2).
// LDS 64KB. Gates: VGPR<=112, WRITE ~16.4MB, conflicts ~4.46M.
// Q,K bf16 [b,h,s,d]; V f16 [b,h,d,s]; O bf16 [b,s,1024].
// Row 2047 (l=0 -> NaN) overwritten by row2047_kernel afterwards.
// ---------------------------------------------------------------------------
#define STAGE_KV(KS, VS, KT)                                                   \
    do {                                                                       \
        _Pragma("unroll")                                                      \
        for (int i_ = 0; i_ < 4; i_++) {                                       \
            int rows8_ = wave * 32 + i_ * 8;                                   \
            gll16(Kh + (size_t)((KT) * 128 + rows8_ + lrow) * HD + (lg ^ lrow) * 8, \
                  (KS) + rows8_ * 64);                                         \
        }                                                                      \
        _Pragma("unroll")                                                      \
        for (int i_ = 0; i_ < 4; i_++) {                                       \
            int rows4_ = wave * 16 + i_ * 4;                                   \
            int row_ = rows4_ + (lane >> 4);                                   \
            int g_ = (lane & 15) ^ (row_ & 15);                                \
            gll16(Vh + (size_t)row_ * SEQ + (KT) * 128 + g_ * 8,               \
                  (VS) + rows4_ * 128);                                        \
        }                                                                      \
    } while (0)

#define PROCESS_SUB(KSB, VSB, KT, DOMASK)                                      \
    do {                                                                       \
        _Pragma("unroll")                                                      \
        for (int jt = 0; jt < 8; jt++) {                                       \
            floatx4 sc0 = {}, sc1 = {};                                        \
            _Pragma("unroll")                                                  \
            for (int c = 0; c < 2; c++) {                                      \
                int row_ = jt * 16 + lm;                                       \
                int g_ = c * 4 + lq;                                           \
                short8 kf = *(const short8*)((KSB) + (row_ * 8 + (g_ ^ (row_ & 7))) * 8); \
                sc0 = __builtin_amdgcn_mfma_f32_16x16x32_bf16(kf, bq0[c], sc0, 0, 0, 0); \
                sc1 = __builtin_amdgcn_mfma_f32_16x16x32_bf16(kf, bq1[c], sc1, 0, 0, 0); \
            }                                                                  \
            if (DOMASK) {                                                      \
                _Pragma("unroll")                                              \
                for (int r = 0; r < 4; r++) {                                  \
                    int kj = (KT) * 128 + jt * 16 + lq * 4 + r;                \
                    if (!(kj > q0)) sc0[r] = -3.2e10f;                         \
                    if (!(kj > q1)) sc1[r] = -3.2e10f;                         \
                }                                                              \
            }                                                                  \
            float p00 = fexp2(sc0[0] * kA), p01 = fexp2(sc0[1] * kA);          \
            float p02 = fexp2(sc0[2] * kA), p03 = fexp2(sc0[3] * kA);          \
            float p10 = fexp2(sc1[0] * kA), p11 = fexp2(sc1[1] * kA);          \
            float p12 = fexp2(sc1[2] * kA), p13 = fexp2(sc1[3] * kA);          \
            l0 += (p00 + p01) + (p02 + p03);                                   \
            l1 += (p10 + p11) + (p12 + p13);                                   \
            h2_t a0_ = __builtin_amdgcn_cvt_pkrtz(p00, p01);                   \
            h2_t b0_ = __builtin_amdgcn_cvt_pkrtz(p02, p03);                   \
            h2_t a1_ = __builtin_amdgcn_cvt_pkrtz(p10, p11);                   \
            h2_t b1_ = __builtin_amdgcn_cvt_pkrtz(p12, p13);                   \
            h4_t pf0, pf1;                                                     \
            pf0[0] = a0_[0]; pf0[1] = a0_[1]; pf0[2] = b0_[0]; pf0[3] = b0_[1];\
            pf1[0] = a1_[0]; pf1[1] = a1_[1]; pf1[2] = b1_[0]; pf1[3] = b1_[1];\
            _Pragma("unroll")                                                  \
            for (int jd = 0; jd < 4; jd++) {                                   \
                int rowv_ = jd * 16 + lm;                                      \
                int g16_ = jt * 2 + (lq >> 1);                                 \
                int slot_ = rowv_ * 16 + (g16_ ^ lm);                          \
                h4_t vf = *(const h4_t*)((VSB) + slot_ * 8 + (lq & 1) * 4);    \
                acc0[jd] = __builtin_amdgcn_mfma_f32_16x16x16f16(vf, pf0, acc0[jd], 0, 0, 0); \
                acc1[jd] = __builtin_amdgcn_mfma_f32_16x16x16f16(vf, pf1, acc1[jd], 0, 0, 0); \
            }                                                                  \
        }                                                                      \
    } while (0)

#define WRITE_O(QROW, ACC, LV)                                                 \
    do {                                                                       \
        float l_ = LV;                                                         \
        l_ += __shfl_xor(l_, 16); l_ += __shfl_xor(l_, 32);                    \
        float inv_ = 1.0f / l_;                                                \
        _Pragma("unroll")                                                      \
        for (int jd = 0; jd < 4; jd++) {                                       \
            bfx4 o_;                                                           \
            _Pragma("unroll")                                                  \
            for (int r = 0; r < 4; r++) o_[r] = (short)f2bf(ACC[jd][r] * inv_);\
            *(bfx4*)(O + (size_t)(b * SEQ + (QROW)) * D_MODEL + h * HD + jd * 16 + lq * 4) = o_; \
        }                                                                      \
    } while (0)

#define DRAIN_BAR()                                                            \
    do {                                                                       \
        asm volatile("s_waitcnt vmcnt(0)" ::: "memory");                       \
        __builtin_amdgcn_s_barrier();                                          \
        __builtin_amdgcn_sched_barrier(0);                                     \
    } while (0)

__global__ __launch_bounds__(256, 2)
void attn11_kernel(const unsigned short* __restrict__ Q,
                   const unsigned short* __restrict__ K,
                   const unsigned short* __restrict__ V,
                   unsigned short* __restrict__ O)
{
    // four DISTINCT objects, each attn8's exact 16KB layout
    __shared__ __align__(16) unsigned short KsA[128 * 64];
    __shared__ __align__(16) unsigned short VsA[64 * 128];
    __shared__ __align__(16) unsigned short KsB[128 * 64];
    __shared__ __align__(16) unsigned short VsB[64 * 128];

    const int t = threadIdx.x;
    const int wave = t >> 6, lane = t & 63;
    const int lm = lane & 15, lq = lane >> 4;

    // XCD swizzle: nwg=1024=8*128; chunk = 8 bh x 16 j per XCD
    const int orig = blockIdx.x;
    const int wkid = (orig & 7) * 128 + (orig >> 3);
    const int bh = wkid >> 4;          // 0..63
    const int j  = wkid & 15;          // q supertile 0..15 (128 rows each)

    const int q0 = j * 128 + wave * 16 + lm;
    const int q1 = q0 + 64;

    const unsigned short* Qh = Q + (size_t)bh * SEQ * HD;
    const unsigned short* Kh = K + (size_t)bh * SEQ * HD;
    const unsigned short* Vh = V + (size_t)bh * HD * SEQ;  // [d][s]

    short8 bq0[2], bq1[2];
#pragma unroll
    for (int c = 0; c < 2; c++) {
        bq0[c] = *(const short8*)(Qh + (size_t)q0 * HD + c * 32 + lq * 8);
        bq1[c] = *(const short8*)(Qh + (size_t)q1 * HD + c * 32 + lq * 8);
    }

    floatx4 acc0[4] = {}, acc1[4] = {};
    float l0 = 0.f, l1 = 0.f;
    const float kA = 0.04508422002778011f;  // log2(e)/32

    const int lrow = lane >> 3, lg = lane & 7;

    // prologue: stage kt=15 into A, full drain once
    STAGE_KV(KsA, VsA, 15);
    DRAIN_BAR();

    int kt = 15;
    while (true) {
        // ---- phase A: prefetch kt-1 into B, compute kt from A ----
        if (kt - 1 >= j) STAGE_KV(KsB, VsB, kt - 1);
        PROCESS_SUB(KsA, (const __fp16*)VsA, kt, (kt == j));
        if (kt - 1 < j) break;
        DRAIN_BAR();          // B landed; all waves done reading A
        kt--;
        // ---- phase B: prefetch kt-1 into A, compute kt from B ----
        if (kt - 1 >= j) STAGE_KV(KsA, VsA, kt - 1);
        PROCESS_SUB(KsB, (const __fp16*)VsB, kt, (kt == j));
        if (kt - 1 < j) break;
        DRAIN_BAR();          // A landed; all waves done reading B
        kt--;
    }

    const int b = bh >> 4, h = bh & 15;
    WRITE_O(q0, acc0, l0);
    WRITE_O(q1, acc1, l1);
}

// ---------------------------------------------------------------------------
// Row 2047 is fully masked -> uniform softmax over ALL keys -> mean of V.
// ---------------------------------------------------------------------------
__global__ __launch_bounds__(256, 2)
void row2047_kernel(const unsigned short* __restrict__ V,
                    unsigned short* __restrict__ O)
{
    __shared__ float red[256];
    const int bh = blockIdx.x;
    const int b = bh >> 4, h = bh & 15;
    const int t = threadIdx.x;
    const int d = t & 63, seg = t >> 6;
    const __fp16* Vh = (const __fp16*)V + (size_t)bh * HD * SEQ + (size_t)d * SEQ + seg * 512;
    float s = 0.f;
    for (int i = 0; i < 512; i += 8) {
        h8_t v = *(const h8_t*)(Vh + i);
#pragma unroll
        for (int j = 0; j < 8; j++) s += (float)v[j];
    }
    red[t] = s;
    __syncthreads();
    if (seg == 0) {
        float tot = red[d] + red[64 + d] + red[128 + d] + red[192 + d];
        O[(size_t)(b * SEQ + 2047) * D_MODEL + h * HD + d] = f2bf(tot * (1.f / 2048.f));
    }
}

// ======================= fallback (ws < 72 MiB) kernels =====================
__global__ __launch_bounds__(256, 2)
void gemm_qkv_kernel(const float* __restrict__ A,
                     const float* __restrict__ W0,
                     const float* __restrict__ W1,
                     const float* __restrict__ W2,
                     unsigned short* __restrict__ O0,
                     unsigned short* __restrict__ O1,
                     unsigned short* __restrict__ O2)
{
    const int K = 1024;
    const float* W;
    unsigned short* Out;
    if (blockIdx.z == 0)      { W = W0; Out = O0; }
    else if (blockIdx.z == 1) { W = W1; Out = O1; }
    else                      { W = W2; Out = O2; }

    __shared__ __align__(16) unsigned short As[128 * 64];
    __shared__ __align__(16) unsigned short Bs[128 * 64];

    const int t = threadIdx.x;
    const int wave = t >> 6, lane = t & 63;
    const int lm = lane & 15, lq = lane >> 4;
    const int wrow = (wave >> 1) * 64, wcol = (wave & 1) * 64;
    const int m0 = blockIdx.x * 128, n0 = blockIdx.y * 128;

    floatx4 acc[4][4] = {};

    for (int k0 = 0; k0 < K; k0 += 64) {
        __syncthreads();
#pragma unroll
        for (int rr = 0; rr < 4; rr++) {
            int p = rr * 256 + t;
            int row = p >> 3, g = p & 7;
            const float* pa = A + (size_t)(m0 + row) * K + k0 + g * 8;
            const float* pw = W + (size_t)(n0 + row) * K + k0 + g * 8;
            floatx4 a0 = *(const floatx4*)pa, a1 = *(const floatx4*)(pa + 4);
            floatx4 w0 = *(const floatx4*)pw, w1 = *(const floatx4*)(pw + 4);
            short8 va, vb;
#pragma unroll
            for (int d = 0; d < 4; d++) {
                va[d]     = (short)f2bf(a0[d]);
                va[4 + d] = (short)f2bf(a1[d]);
                vb[d]     = (short)f2bf(w0[d]);
                vb[4 + d] = (short)f2bf(w1[d]);
            }
            int dst = row * 8 + (g ^ (row & 7));
            *(short8*)(As + dst * 8) = va;
            *(short8*)(Bs + dst * 8) = vb;
        }
        __syncthreads();

        short8 af[4][2], bf[4][2];
#pragma unroll
        for (int i = 0; i < 4; i++)
#pragma unroll
            for (int c = 0; c < 2; c++) {
                int ra = wrow + i * 16 + lm;
                int rb = wcol + i * 16 + lm;
                int g = c * 4 + lq;
                af[i][c] = *(const short8*)(As + (ra * 8 + (g ^ (ra & 7))) * 8);
                bf[i][c] = *(const short8*)(Bs + (rb * 8 + (g ^ (rb & 7))) * 8);
            }
#pragma unroll
        for (int i = 0; i < 4; i++)
#pragma unroll
            for (int j = 0; j < 4; j++)
#pragma unroll
                for (int c = 0; c < 2; c++)
                    acc[i][j] = __builtin_amdgcn_mfma_f32_16x16x32_bf16(
                        af[i][c], bf[j][c], acc[i][j], 0, 0, 0);
    }

    const int zi = blockIdx.z;
#pragma unroll
    for (int i = 0; i < 4; i++)
#pragma unroll
        for (int j = 0; j < 4; j++)
#pragma unroll
            for (int r = 0; r < 4; r++) {
                int gm = m0 + wrow + i * 16 + lq * 4 + r;
                int gn = n0 + wcol + j * 16 + lm;
                int b = gm >> 11, s = gm & 2047;
                int h = gn >> 6, d = gn & 63;
                if (zi == 2) {
                    Out[((size_t)(b * NH + h) * HD + d) * SEQ + s] = f2h(acc[i][j][r]);
                } else {
                    Out[((size_t)(b * NH + h) * SEQ + s) * HD + d] = f2bf(acc[i][j][r]);
                }
            }
}

__global__ __launch_bounds__(256, 2)
void gemm_out_kernel(const unsigned short* __restrict__ Abf,
                     const float* __restrict__ W,
                     float* __restrict__ Out)
{
    const int K = 1024;
    __shared__ __align__(16) unsigned short As[128 * 64];
    __shared__ __align__(16) unsigned short Bs[128 * 64];

    const int t = threadIdx.x;
    const int wave = t >> 6, lane = t & 63;
    const int lm = lane & 15, lq = lane >> 4;
    const int wrow = (wave >> 1) * 64, wcol = (wave & 1) * 64;
    const int m0 = blockIdx.x * 128, n0 = blockIdx.y * 128;

    floatx4 acc[4][4] = {};

    for (int k0 = 0; k0 < K; k0 += 64) {
        __syncthreads();
#pragma unroll
        for (int rr = 0; rr < 4; rr++) {
            int p = rr * 256 + t;
            int row = p >> 3, g = p & 7;
            short8 va = *(const short8*)(Abf + (size_t)(m0 + row) * K + k0 + g * 8);
            const float* pw = W + (size_t)(n0 + row) * K + k0 + g * 8;
            floatx4 w0 = *(const floatx4*)pw, w1 = *(const floatx4*)(pw + 4);
            short8 vb;
#pragma unroll
            for (int d = 0; d < 4; d++) {
                vb[d]     = (short)f2bf(w0[d]);
                vb[4 + d] = (short)f2bf(w1[d]);
            }
            int dst = row * 8 + (g ^ (row & 7));
            *(short8*)(As + dst * 8) = va;
            *(short8*)(Bs + dst * 8) = vb;
        }
        __syncthreads();

        short8 af[4][2], bf[4][2];
#pragma unroll
        for (int i = 0; i < 4; i++)
#pragma unroll
            for (int c = 0; c < 2; c++) {
                int ra = wrow + i * 16 + lm;
                int rb = wcol + i * 16 + lm;
                int g = c * 4 + lq;
                af[i][c] = *(const short8*)(As + (ra * 8 + (g ^ (ra & 7))) * 8);
                bf[i][c] = *(const short8*)(Bs + (rb * 8 + (g ^ (rb & 7))) * 8);
            }
#pragma unroll
        for (int i = 0; i < 4; i++)
#pragma unroll
            for (int j = 0; j < 4; j++)
#pragma unroll
                for (int c = 0; c < 2; c++)
                    acc[i][j] = __builtin_amdgcn_mfma_f32_16x16x32_bf16(
                        af[i][c], bf[j][c], acc[i][j], 0, 0, 0);
    }

#pragma unroll
    for (int i = 0; i < 4; i++)
#pragma unroll
        for (int j = 0; j < 4; j++)
#pragma unroll
            for (int r = 0; r < 4; r++) {
                int gm = m0 + wrow + i * 16 + lq * 4 + r;
                int gn = n0 + wcol + j * 16 + lm;
                Out[(size_t)gm * D_MODEL + gn] = acc[i][j][r];
            }
}

extern "C" void kernel_launch(void* const* d_in, const int* in_sizes, int n_in,
                              void* d_out, int out_size, void* d_ws, size_t ws_size,
                              hipStream_t stream) {
    const float* x  = (const float*)d_in[0];
    const float* wq = (const float*)d_in[1];
    const float* wk = (const float*)d_in[2];
    const float* wv = (const float*)d_in[3];
    const float* wo = (const float*)d_in[4];

    unsigned short* ws = (unsigned short*)d_ws;
    const bool fast = ws_size >= (size_t)36 * 1024 * 1024 * 2;  // 72 MiB

    if (fast) {
        unsigned short* xbf  = ws;                     // 8M elems; reused as Ob
        unsigned short* wqkv = ws + (size_t)ELEMS;     // 3M
        unsigned short* wobf = ws + (size_t)ELEMS + 3 * WELEMS;  // 1M
        unsigned short* Qb   = ws + (size_t)ELEMS + 4 * WELEMS;  // 8M
        unsigned short* Kb   = Qb + ELEMS;
        unsigned short* Vb   = Kb + ELEMS;
        unsigned short* Ob   = xbf;                    // x_bf dead after QKV GEMM

        cvt_kernel<<<6144, 256, 0, stream>>>(x, wq, wk, wv, wo, xbf, wqkv, wobf);
        gemm_qkv3_kernel<<<dim3(64, 24), 256, 0, stream>>>(xbf, wqkv, Qb, Kb, Vb);
        attn11_kernel<<<1024, 256, 0, stream>>>(Qb, Kb, Vb, Ob);
        row2047_kernel<<<BATCH * NH, 256, 0, stream>>>(Vb, Ob);
        gemm_out3_kernel<<<dim3(64, 8), 256, 0, stream>>>(Ob, wobf, (float*)d_out);
    } else {
        unsigned short* Qb = ws;
        unsigned short* Kb = Qb + ELEMS;
        unsigned short* Vb = Kb + ELEMS;
        unsigned short* Ob = Vb + ELEMS;

        gemm_qkv_kernel<<<dim3(64, 8, 3), 256, 0, stream>>>(x, wq, wk, wv, Qb, Kb, Vb);
        attn11_kernel<<<1024, 256, 0, stream>>>(Qb, Kb, Vb, Ob);
        row2047_kernel<<<BATCH * NH, 256, 0, stream>>>(Vb, Ob);
        gemm_out_kernel<<<dim3(64, 8), 256, 0, stream>>>(Ob, wo, (float*)d_out);
    }
}

// Round 11
// 266.436 us; speedup vs baseline: 1.0777x; 1.0138x over previous
//
#include <hip/hip_runtime.h>
#include <hip/hip_bf16.h>

typedef __attribute__((ext_vector_type(8))) short short8;
typedef __attribute__((ext_vector_type(4))) short bfx4;
typedef __attribute__((ext_vector_type(4))) float floatx4;
typedef __attribute__((ext_vector_type(4))) __fp16 h4_t;
typedef __attribute__((ext_vector_type(2))) __fp16 h2_t;
typedef __attribute__((ext_vector_type(8))) __fp16 h8_t;

#define BATCH 4
#define SEQ 2048
#define D_MODEL 1024
#define NH 16
#define HD 64
#define ELEMS 8388608   // B*S*D = 4*2048*1024
#define WELEMS 1048576  // 1024*1024

// fp32 -> bf16 round-to-nearest-even
__device__ __forceinline__ unsigned short f2bf(float f) {
    union { float f; unsigned u; } x; x.f = f;
    unsigned r = x.u + 0x7FFFu + ((x.u >> 16) & 1u);
    return (unsigned short)(r >> 16);
}
__device__ __forceinline__ unsigned short f2h(float f) {
    union { __fp16 h; unsigned short u; } x;
    x.h = (__fp16)f;
    return x.u;
}

#if __has_builtin(__builtin_amdgcn_exp2f)
__device__ __forceinline__ float fexp2(float x) { return __builtin_amdgcn_exp2f(x); }
#else
__device__ __forceinline__ float fexp2(float x) { return exp2f(x); }
#endif

// async global->LDS, 16B per lane; HW dest = wave-uniform base + lane*16
__device__ __forceinline__ void gll16(const void* g, const void* l) {
    __builtin_amdgcn_global_load_lds(
        (const __attribute__((address_space(1))) void*)g,
        (__attribute__((address_space(3))) void*)l,
        16, 0, 0);
}

// NOTE (session post-mortems):
//  - R1: 8-phase 256^2 counted-vmcnt GEMM port regressed. Abandoned.
//  - R2: dbuf attn with __syncthreads regressed.
//  - R3: 128^2 GEMM tiles > 128x256 at K=1024.
//  - R4: attn7 spilled at the 128-VGPR cap. FETCH/WRITE blowup = spill sig.
//  - R5: attn8 (2 acc sets, K/V-read reuse across 2 Q-frags): 107us.
//  - R6: attn XCD swizzle WIN (107->86.5, FETCH 110->24.6MB). GEMM swizzle
//    regressed. Reverted.
//  - R7: recombined -> 268.5us best.
//  - R8: attn9 KVBLK=256 regressed on two impl defects.
//  - R9: attn10 fixed both defects -> 87.9 = attn8. KVBLK axis dead.
//  - R10: attn11 true-dbuf (distinct LDS objects, compile-time buffers,
//    raw s_barrier + vmcnt-after-compute): gates passed, dur FLAT at 87.2.
//    THREE schedule-invariant nulls => the wall is not the schedule.
//    Re-derivation: grid 1024 = exactly 4 blocks/CU, no refill. wkid order
//    was bh-major/j-minor -> under initial-fill round-robin a CU's four
//    slots (p, p+32, p+64, p+96) all have the SAME j ((p+32k)&15): j=0 CUs
//    get 64 tile-visits, j=15 CUs get 4. Maximal imbalance = the 13%
//    occupancy and the schedule-proof 87us wall.
//  - R11 (this round): attn12 = attn8 body + BALANCED block order: within
//    each XCD chunk, slots p,p+32,p+64,p+96 carry j = {a,15-a,a,15-a} ->
//    every CU totals 34 tile-visits (the mean). Pure index permutation.
//    Also out3 -> out4: 128x64 tile, grid (64,16)=1024=4/CU (out3 at 2/CU
//    single-round was the worst per-FLOP kernel).

// ---------------------------------------------------------------------------
// cvt: x (8M), wq|wk|wv (3M, concatenated), wo (1M) fp32 -> bf16
// ---------------------------------------------------------------------------
__global__ __launch_bounds__(256)
void cvt_kernel(const float* __restrict__ x,  const float* __restrict__ wq,
                const float* __restrict__ wk, const float* __restrict__ wv,
                const float* __restrict__ wo,
                unsigned short* __restrict__ xbf,
                unsigned short* __restrict__ wqkv,
                unsigned short* __restrict__ wobf)
{
    size_t idx = ((size_t)blockIdx.x * 256 + threadIdx.x) * 8;
    const float* src; unsigned short* dst; size_t off;
    if (idx < (size_t)ELEMS)                    { src = x;  dst = xbf;             off = idx; }
    else if (idx < (size_t)ELEMS + WELEMS)      { src = wq; dst = wqkv;            off = idx - ELEMS; }
    else if (idx < (size_t)ELEMS + 2 * WELEMS)  { src = wk; dst = wqkv + WELEMS;   off = idx - ELEMS - WELEMS; }
    else if (idx < (size_t)ELEMS + 3 * WELEMS)  { src = wv; dst = wqkv + 2*WELEMS; off = idx - ELEMS - 2*WELEMS; }
    else                                        { src = wo; dst = wobf;            off = idx - ELEMS - 3*WELEMS; }
    floatx4 a = *(const floatx4*)(src + off);
    floatx4 b = *(const floatx4*)(src + off + 4);
    short8 v;
#pragma unroll
    for (int d = 0; d < 4; d++) { v[d] = (short)f2bf(a[d]); v[4+d] = (short)f2bf(b[d]); }
    *(short8*)(dst + off) = v;
}

// ---------------------------------------------------------------------------
// QKV GEMM, 128x128 tile (R3/R5/R7 proven, default 2D dispatch): A=x_bf
// [8192,1024], B=wqkv_bf [3072,1024] (NT), staged via global_load_lds with
// inverse-XOR-swizzled source. BK=64, 32 KiB LDS. Grid (64,24).
// ---------------------------------------------------------------------------
__global__ __launch_bounds__(256, 2)
void gemm_qkv3_kernel(const unsigned short* __restrict__ A,
                      const unsigned short* __restrict__ B,
                      unsigned short* __restrict__ Qb,
                      unsigned short* __restrict__ Kb,
                      unsigned short* __restrict__ Vb)
{
    __shared__ __align__(16) unsigned short As[128 * 64];
    __shared__ __align__(16) unsigned short Bs[128 * 64];

    const int t = threadIdx.x;
    const int wave = t >> 6, lane = t & 63;
    const int lm = lane & 15, lq = lane >> 4;
    const int wrow = (wave >> 1) * 64, wcol = (wave & 1) * 64;
    const int m0 = blockIdx.x * 128, n0 = blockIdx.y * 128;
    const int lrow = lane >> 3, lg = lane & 7;
    const int gsw = lg ^ lrow;

    floatx4 acc[4][4] = {};

    for (int k0 = 0; k0 < 1024; k0 += 64) {
        __syncthreads();
#pragma unroll
        for (int i = 0; i < 4; i++) {
            int rows8 = wave * 32 + i * 8;
            gll16(A + (size_t)(m0 + rows8 + lrow) * 1024 + k0 + gsw * 8, As + rows8 * 64);
            gll16(B + (size_t)(n0 + rows8 + lrow) * 1024 + k0 + gsw * 8, Bs + rows8 * 64);
        }
        __syncthreads();

#pragma unroll
        for (int c = 0; c < 2; c++) {
            short8 af[4], bfr[4];
#pragma unroll
            for (int i = 0; i < 4; i++) {
                int ra = wrow + i * 16 + lm;
                int g = c * 4 + lq;
                af[i] = *(const short8*)(As + (ra * 8 + (g ^ (ra & 7))) * 8);
            }
#pragma unroll
            for (int j = 0; j < 4; j++) {
                int rb = wcol + j * 16 + lm;
                int g = c * 4 + lq;
                bfr[j] = *(const short8*)(Bs + (rb * 8 + (g ^ (rb & 7))) * 8);
            }
#pragma unroll
            for (int i = 0; i < 4; i++)
#pragma unroll
                for (int j = 0; j < 4; j++)
                    acc[i][j] = __builtin_amdgcn_mfma_f32_16x16x32_bf16(
                        af[i], bfr[j], acc[i][j], 0, 0, 0);
        }
    }

    const int z = n0 >> 10;   // 0=Q 1=K 2=V, uniform per block
#pragma unroll
    for (int i = 0; i < 4; i++)
#pragma unroll
        for (int j = 0; j < 4; j++)
#pragma unroll
            for (int r = 0; r < 4; r++) {
                int gm = m0 + wrow + i * 16 + lq * 4 + r;
                int gn = n0 + wcol + j * 16 + lm;
                int nl = gn & 1023, h = nl >> 6, d = nl & 63;
                int b = gm >> 11, s = gm & 2047;
                float v = acc[i][j][r];
                size_t bh = (size_t)(b * NH + h);
                if (z == 0)      Qb[(bh * SEQ + s) * HD + d] = f2bf(v);
                else if (z == 1) Kb[(bh * SEQ + s) * HD + d] = f2bf(v);
                else             Vb[(bh * HD + d) * SEQ + s] = f2h(v);
            }
}

// ---------------------------------------------------------------------------
// Output projection v4: 128x64 tile, grid (64,16)=1024 blocks = 4/CU
// (out3 at (64,8)=512=2/CU single-round was the worst per-FLOP kernel:
// per-K-step drains exposed with only 2-way TLP). 24 KiB LDS, acc[4][2].
// A=Ob bf16 [8192,1024], B=wo_bf [1024,1024] -> fp32.
// ---------------------------------------------------------------------------
__global__ __launch_bounds__(256, 2)
void gemm_out4_kernel(const unsigned short* __restrict__ A,
                      const unsigned short* __restrict__ B,
                      float* __restrict__ Out)
{
    __shared__ __align__(16) unsigned short As[128 * 64];  // 16 KB
    __shared__ __align__(16) unsigned short Bs[64 * 64];   // 8 KB

    const int t = threadIdx.x;
    const int wave = t >> 6, lane = t & 63;
    const int lm = lane & 15, lq = lane >> 4;
    const int wrow = (wave >> 1) * 64, wcol = (wave & 1) * 32;
    const int m0 = blockIdx.x * 128, n0 = blockIdx.y * 64;
    const int lrow = lane >> 3, lg = lane & 7;
    const int gsw = lg ^ lrow;

    floatx4 acc[4][2] = {};

    for (int k0 = 0; k0 < 1024; k0 += 64) {
        __syncthreads();
#pragma unroll
        for (int i = 0; i < 4; i++) {
            int rows8 = wave * 32 + i * 8;
            gll16(A + (size_t)(m0 + rows8 + lrow) * 1024 + k0 + gsw * 8, As + rows8 * 64);
        }
#pragma unroll
        for (int i = 0; i < 2; i++) {
            int rows8 = wave * 16 + i * 8;
            gll16(B + (size_t)(n0 + rows8 + lrow) * 1024 + k0 + gsw * 8, Bs + rows8 * 64);
        }
        __syncthreads();

#pragma unroll
        for (int c = 0; c < 2; c++) {
            short8 af[4], bfr[2];
#pragma unroll
            for (int i = 0; i < 4; i++) {
                int ra = wrow + i * 16 + lm;
                int g = c * 4 + lq;
                af[i] = *(const short8*)(As + (ra * 8 + (g ^ (ra & 7))) * 8);
            }
#pragma unroll
            for (int j = 0; j < 2; j++) {
                int rb = wcol + j * 16 + lm;
                int g = c * 4 + lq;
                bfr[j] = *(const short8*)(Bs + (rb * 8 + (g ^ (rb & 7))) * 8);
            }
#pragma unroll
            for (int i = 0; i < 4; i++)
#pragma unroll
                for (int j = 0; j < 2; j++)
                    acc[i][j] = __builtin_amdgcn_mfma_f32_16x16x32_bf16(
                        af[i], bfr[j], acc[i][j], 0, 0, 0);
        }
    }

#pragma unroll
    for (int i = 0; i < 4; i++)
#pragma unroll
        for (int j = 0; j < 2; j++)
#pragma unroll
            for (int r = 0; r < 4; r++) {
                int gm = m0 + wrow + i * 16 + lq * 4 + r;
                int gn = n0 + wcol + j * 16 + lm;
                Out[(size_t)gm * D_MODEL + gn] = acc[i][j][r];
            }
}

// ---------------------------------------------------------------------------
// Flash attention v12: attn8 body (R5/R6 proven: 2 Q-frags/wave, KVBLK=128,
// single-buffer, XCD swizzle) + BALANCED per-CU work order.
// Within each XCD chunk of 128 blocks (8 bh x 16 j): position p (=orig>>3)
// decomposes as q=p&31 (CU slot), g=p>>5 (slot group). j alternates
// a / 15-a across groups so a CU's four slots total 34 tile-visits (mean);
// the old bh-major/j-minor order gave a CU four IDENTICAL j's (4..64
// visits, 13% occupancy, schedule-proof 87us wall — R8/R9/R10 nulls).
// bh = chunk*8 + (q>>4) + 2*g keeps R6's per-XCD K/V L2 locality.
// Q,K bf16 [b,h,s,d]; V f16 [b,h,d,s]; O bf16 [b,s,1024].
// Row 2047 (l=0 -> NaN) overwritten by row2047_kernel afterwards.
// ---------------------------------------------------------------------------
#define PROCESS_Q2(QI0, QI1, BQ0, BQ1, ACC0, ACC1, L0, L1, DOMASK, KT)         \
    do {                                                                       \
        _Pragma("unroll")                                                      \
        for (int jt = 0; jt < 8; jt++) {                                       \
            floatx4 sc0 = {}, sc1 = {};                                        \
            _Pragma("unroll")                                                  \
            for (int c = 0; c < 2; c++) {                                      \
                int row_ = jt * 16 + lm;                                       \
                int g_ = c * 4 + lq;                                           \
                short8 kf = *(const short8*)(Ks + (row_ * 8 + (g_ ^ (row_ & 7))) * 8); \
                sc0 = __builtin_amdgcn_mfma_f32_16x16x32_bf16(kf, BQ0[c], sc0, 0, 0, 0); \
                sc1 = __builtin_amdgcn_mfma_f32_16x16x32_bf16(kf, BQ1[c], sc1, 0, 0, 0); \
            }                                                                  \
            if (DOMASK) {                                                      \
                _Pragma("unroll")                                              \
                for (int r = 0; r < 4; r++) {                                  \
                    int kj = (KT) * 128 + jt * 16 + lq * 4 + r;                \
                    if (!(kj > (QI0))) sc0[r] = -3.2e10f;                      \
                    if (!(kj > (QI1))) sc1[r] = -3.2e10f;                      \
                }                                                              \
            }                                                                  \
            float p00 = fexp2(sc0[0] * kA), p01 = fexp2(sc0[1] * kA);          \
            float p02 = fexp2(sc0[2] * kA), p03 = fexp2(sc0[3] * kA);          \
            float p10 = fexp2(sc1[0] * kA), p11 = fexp2(sc1[1] * kA);          \
            float p12 = fexp2(sc1[2] * kA), p13 = fexp2(sc1[3] * kA);          \
            L0 += (p00 + p01) + (p02 + p03);                                   \
            L1 += (p10 + p11) + (p12 + p13);                                   \
            h2_t a0_ = __builtin_amdgcn_cvt_pkrtz(p00, p01);                   \
            h2_t b0_ = __builtin_amdgcn_cvt_pkrtz(p02, p03);                   \
            h2_t a1_ = __builtin_amdgcn_cvt_pkrtz(p10, p11);                   \
            h2_t b1_ = __builtin_amdgcn_cvt_pkrtz(p12, p13);                   \
            h4_t pf0, pf1;                                                     \
            pf0[0] = a0_[0]; pf0[1] = a0_[1]; pf0[2] = b0_[0]; pf0[3] = b0_[1];\
            pf1[0] = a1_[0]; pf1[1] = a1_[1]; pf1[2] = b1_[0]; pf1[3] = b1_[1];\
            _Pragma("unroll")                                                  \
            for (int jd = 0; jd < 4; jd++) {                                   \
                int rowv_ = jd * 16 + lm;                                      \
                int g16_ = jt * 2 + (lq >> 1);                                 \
                int slot_ = rowv_ * 16 + (g16_ ^ lm);                          \
                h4_t vf = *(const h4_t*)((const __fp16*)Vs + slot_ * 8 + (lq & 1) * 4); \
                ACC0[jd] = __builtin_amdgcn_mfma_f32_16x16x16f16(vf, pf0, ACC0[jd], 0, 0, 0); \
                ACC1[jd] = __builtin_amdgcn_mfma_f32_16x16x16f16(vf, pf1, ACC1[jd], 0, 0, 0); \
            }                                                                  \
        }                                                                      \
    } while (0)

#define WRITE_O(QROW, ACC, LV)                                                 \
    do {                                                                       \
        float l_ = LV;                                                         \
        l_ += __shfl_xor(l_, 16); l_ += __shfl_xor(l_, 32);                    \
        float inv_ = 1.0f / l_;                                                \
        _Pragma("unroll")                                                      \
        for (int jd = 0; jd < 4; jd++) {                                       \
            bfx4 o_;                                                           \
            _Pragma("unroll")                                                  \
            for (int r = 0; r < 4; r++) o_[r] = (short)f2bf(ACC[jd][r] * inv_);\
            *(bfx4*)(O + (size_t)(b * SEQ + (QROW)) * D_MODEL + h * HD + jd * 16 + lq * 4) = o_; \
        }                                                                      \
    } while (0)

__global__ __launch_bounds__(256, 2)
void attn12_kernel(const unsigned short* __restrict__ Q,
                   const unsigned short* __restrict__ K,
                   const unsigned short* __restrict__ V,
                   unsigned short* __restrict__ O)
{
    __shared__ __align__(16) unsigned short Ks[128 * 64];  // [key][d] swizzled bf16
    __shared__ __align__(16) unsigned short Vs[64 * 128];  // [d][key] swizzled f16

    const int t = threadIdx.x;
    const int wave = t >> 6, lane = t & 63;
    const int lm = lane & 15, lq = lane >> 4;

    // Balanced XCD mapping: chunk = orig&7 (XCD), p = orig>>3 in [0,128).
    // q = p&31 (CU slot within XCD), g = p>>5 (slot group 0..3).
    // j alternates a / 15-a across groups -> per-CU tile total = 34.
    const int orig = blockIdx.x;
    const int p = orig >> 3;
    const int q = p & 31, g = p >> 5;
    const int jq = q & 15;
    const int j = (g & 1) ? (15 - jq) : jq;
    const int bh = (orig & 7) * 8 + (q >> 4) + 2 * g;

    const int q0 = j * 128 + wave * 16 + lm;
    const int q1 = q0 + 64;

    const unsigned short* Qh = Q + (size_t)bh * SEQ * HD;
    const unsigned short* Kh = K + (size_t)bh * SEQ * HD;
    const unsigned short* Vh = V + (size_t)bh * HD * SEQ;  // [d][s]

    short8 bq0[2], bq1[2];
#pragma unroll
    for (int c = 0; c < 2; c++) {
        bq0[c] = *(const short8*)(Qh + (size_t)q0 * HD + c * 32 + lq * 8);
        bq1[c] = *(const short8*)(Qh + (size_t)q1 * HD + c * 32 + lq * 8);
    }

    floatx4 acc0[4] = {}, acc1[4] = {};
    float l0 = 0.f, l1 = 0.f;
    const float kA = 0.04508422002778011f;  // log2(e)/32

    const int lrow = lane >> 3, lg = lane & 7;

    for (int kt = 15; kt >= j; kt--) {
        __syncthreads();
        // K tile: 128 keys x 64 d
#pragma unroll
        for (int i = 0; i < 4; i++) {
            int rows8 = wave * 32 + i * 8;
            gll16(Kh + (size_t)(kt * 128 + rows8 + lrow) * HD + (lg ^ lrow) * 8,
                  Ks + rows8 * 64);
        }
        // V^T tile: 64 d x 128 keys
#pragma unroll
        for (int i = 0; i < 4; i++) {
            int rows4 = wave * 16 + i * 4;
            int row = rows4 + (lane >> 4);
            int gx = (lane & 15) ^ (row & 15);
            gll16(Vh + (size_t)row * SEQ + kt * 128 + gx * 8, Vs + rows4 * 128);
        }
        __syncthreads();

        PROCESS_Q2(q0, q1, bq0, bq1, acc0, acc1, l0, l1, (kt == j), kt);
    }

    const int b = bh >> 4, h = bh & 15;
    WRITE_O(q0, acc0, l0);
    WRITE_O(q1, acc1, l1);
}

// ---------------------------------------------------------------------------
// Row 2047 is fully masked -> uniform softmax over ALL keys -> mean of V.
// ---------------------------------------------------------------------------
__global__ __launch_bounds__(256, 2)
void row2047_kernel(const unsigned short* __restrict__ V,
                    unsigned short* __restrict__ O)
{
    __shared__ float red[256];
    const int bh = blockIdx.x;
    const int b = bh >> 4, h = bh & 15;
    const int t = threadIdx.x;
    const int d = t & 63, seg = t >> 6;
    const __fp16* Vh = (const __fp16*)V + (size_t)bh * HD * SEQ + (size_t)d * SEQ + seg * 512;
    float s = 0.f;
    for (int i = 0; i < 512; i += 8) {
        h8_t v = *(const h8_t*)(Vh + i);
#pragma unroll
        for (int j = 0; j < 8; j++) s += (float)v[j];
    }
    red[t] = s;
    __syncthreads();
    if (seg == 0) {
        float tot = red[d] + red[64 + d] + red[128 + d] + red[192 + d];
        O[(size_t)(b * SEQ + 2047) * D_MODEL + h * HD + d] = f2bf(tot * (1.f / 2048.f));
    }
}

// ======================= fallback (ws < 72 MiB) kernels =====================
__global__ __launch_bounds__(256, 2)
void gemm_qkv_kernel(const float* __restrict__ A,
                     const float* __restrict__ W0,
                     const float* __restrict__ W1,
                     const float* __restrict__ W2,
                     unsigned short* __restrict__ O0,
                     unsigned short* __restrict__ O1,
                     unsigned short* __restrict__ O2)
{
    const int K = 1024;
    const float* W;
    unsigned short* Out;
    if (blockIdx.z == 0)      { W = W0; Out = O0; }
    else if (blockIdx.z == 1) { W = W1; Out = O1; }
    else                      { W = W2; Out = O2; }

    __shared__ __align__(16) unsigned short As[128 * 64];
    __shared__ __align__(16) unsigned short Bs[128 * 64];

    const int t = threadIdx.x;
    const int wave = t >> 6, lane = t & 63;
    const int lm = lane & 15, lq = lane >> 4;
    const int wrow = (wave >> 1) * 64, wcol = (wave & 1) * 64;
    const int m0 = blockIdx.x * 128, n0 = blockIdx.y * 128;

    floatx4 acc[4][4] = {};

    for (int k0 = 0; k0 < K; k0 += 64) {
        __syncthreads();
#pragma unroll
        for (int rr = 0; rr < 4; rr++) {
            int p = rr * 256 + t;
            int row = p >> 3, g = p & 7;
            const float* pa = A + (size_t)(m0 + row) * K + k0 + g * 8;
            const float* pw = W + (size_t)(n0 + row) * K + k0 + g * 8;
            floatx4 a0 = *(const floatx4*)pa, a1 = *(const floatx4*)(pa + 4);
            floatx4 w0 = *(const floatx4*)pw, w1 = *(const floatx4*)(pw + 4);
            short8 va, vb;
#pragma unroll
            for (int d = 0; d < 4; d++) {
                va[d]     = (short)f2bf(a0[d]);
                va[4 + d] = (short)f2bf(a1[d]);
                vb[d]     = (short)f2bf(w0[d]);
                vb[4 + d] = (short)f2bf(w1[d]);
            }
            int dst = row * 8 + (g ^ (row & 7));
            *(short8*)(As + dst * 8) = va;
            *(short8*)(Bs + dst * 8) = vb;
        }
        __syncthreads();

        short8 af[4][2], bf[4][2];
#pragma unroll
        for (int i = 0; i < 4; i++)
#pragma unroll
            for (int c = 0; c < 2; c++) {
                int ra = wrow + i * 16 + lm;
                int rb = wcol + i * 16 + lm;
                int g = c * 4 + lq;
                af[i][c] = *(const short8*)(As + (ra * 8 + (g ^ (ra & 7))) * 8);
                bf[i][c] = *(const short8*)(Bs + (rb * 8 + (g ^ (rb & 7))) * 8);
            }
#pragma unroll
        for (int i = 0; i < 4; i++)
#pragma unroll
            for (int j = 0; j < 4; j++)
#pragma unroll
                for (int c = 0; c < 2; c++)
                    acc[i][j] = __builtin_amdgcn_mfma_f32_16x16x32_bf16(
                        af[i][c], bf[j][c], acc[i][j], 0, 0, 0);
    }

    const int zi = blockIdx.z;
#pragma unroll
    for (int i = 0; i < 4; i++)
#pragma unroll
        for (int j = 0; j < 4; j++)
#pragma unroll
            for (int r = 0; r < 4; r++) {
                int gm = m0 + wrow + i * 16 + lq * 4 + r;
                int gn = n0 + wcol + j * 16 + lm;
                int b = gm >> 11, s = gm & 2047;
                int h = gn >> 6, d = gn & 63;
                if (zi == 2) {
                    Out[((size_t)(b * NH + h) * HD + d) * SEQ + s] = f2h(acc[i][j][r]);
                } else {
                    Out[((size_t)(b * NH + h) * SEQ + s) * HD + d] = f2bf(acc[i][j][r]);
                }
            }
}

__global__ __launch_bounds__(256, 2)
void gemm_out_kernel(const unsigned short* __restrict__ Abf,
                     const float* __restrict__ W,
                     float* __restrict__ Out)
{
    const int K = 1024;
    __shared__ __align__(16) unsigned short As[128 * 64];
    __shared__ __align__(16) unsigned short Bs[128 * 64];

    const int t = threadIdx.x;
    const int wave = t >> 6, lane = t & 63;
    const int lm = lane & 15, lq = lane >> 4;
    const int wrow = (wave >> 1) * 64, wcol = (wave & 1) * 64;
    const int m0 = blockIdx.x * 128, n0 = blockIdx.y * 128;

    floatx4 acc[4][4] = {};

    for (int k0 = 0; k0 < K; k0 += 64) {
        __syncthreads();
#pragma unroll
        for (int rr = 0; rr < 4; rr++) {
            int p = rr * 256 + t;
            int row = p >> 3, g = p & 7;
            short8 va = *(const short8*)(Abf + (size_t)(m0 + row) * K + k0 + g * 8);
            const float* pw = W + (size_t)(n0 + row) * K + k0 + g * 8;
            floatx4 w0 = *(const floatx4*)pw, w1 = *(const floatx4*)(pw + 4);
            short8 vb;
#pragma unroll
            for (int d = 0; d < 4; d++) {
                vb[d]     = (short)f2bf(w0[d]);
                vb[4 + d] = (short)f2bf(w1[d]);
            }
            int dst = row * 8 + (g ^ (row & 7));
            *(short8*)(As + dst * 8) = va;
            *(short8*)(Bs + dst * 8) = vb;
        }
        __syncthreads();

        short8 af[4][2], bf[4][2];
#pragma unroll
        for (int i = 0; i < 4; i++)
#pragma unroll
            for (int c = 0; c < 2; c++) {
                int ra = wrow + i * 16 + lm;
                int rb = wcol + i * 16 + lm;
                int g = c * 4 + lq;
                af[i][c] = *(const short8*)(As + (ra * 8 + (g ^ (ra & 7))) * 8);
                bf[i][c] = *(const short8*)(Bs + (rb * 8 + (g ^ (rb & 7))) * 8);
            }
#pragma unroll
        for (int i = 0; i < 4; i++)
#pragma unroll
            for (int j = 0; j < 4; j++)
#pragma unroll
                for (int c = 0; c < 2; c++)
                    acc[i][j] = __builtin_amdgcn_mfma_f32_16x16x32_bf16(
                        af[i][c], bf[j][c], acc[i][j], 0, 0, 0);
    }

#pragma unroll
    for (int i = 0; i < 4; i++)
#pragma unroll
        for (int j = 0; j < 4; j++)
#pragma unroll
            for (int r = 0; r < 4; r++) {
                int gm = m0 + wrow + i * 16 + lq * 4 + r;
                int gn = n0 + wcol + j * 16 + lm;
                Out[(size_t)gm * D_MODEL + gn] = acc[i][j][r];
            }
}

extern "C" void kernel_launch(void* const* d_in, const int* in_sizes, int n_in,
                              void* d_out, int out_size, void* d_ws, size_t ws_size,
                              hipStream_t stream) {
    const float* x  = (const float*)d_in[0];
    const float* wq = (const float*)d_in[1];
    const float* wk = (const float*)d_in[2];
    const float* wv = (const float*)d_in[3];
    const float* wo = (const float*)d_in[4];

    unsigned short* ws = (unsigned short*)d_ws;
    const bool fast = ws_size >= (size_t)36 * 1024 * 1024 * 2;  // 72 MiB

    if (fast) {
        unsigned short* xbf  = ws;                     // 8M elems; reused as Ob
        unsigned short* wqkv = ws + (size_t)ELEMS;     // 3M
        unsigned short* wobf = ws + (size_t)ELEMS + 3 * WELEMS;  // 1M
        unsigned short* Qb   = ws + (size_t)ELEMS + 4 * WELEMS;  // 8M
        unsigned short* Kb   = Qb + ELEMS;
        unsigned short* Vb   = Kb + ELEMS;
        unsigned short* Ob   = xbf;                    // x_bf dead after QKV GEMM

        cvt_kernel<<<6144, 256, 0, stream>>>(x, wq, wk, wv, wo, xbf, wqkv, wobf);
        gemm_qkv3_kernel<<<dim3(64, 24), 256, 0, stream>>>(xbf, wqkv, Qb, Kb, Vb);
        attn12_kernel<<<1024, 256, 0, stream>>>(Qb, Kb, Vb, Ob);
        row2047_kernel<<<BATCH * NH, 256, 0, stream>>>(Vb, Ob);
        gemm_out4_kernel<<<dim3(64, 16), 256, 0, stream>>>(Ob, wobf, (float*)d_out);
    } else {
        unsigned short* Qb = ws;
        unsigned short* Kb = Qb + ELEMS;
        unsigned short* Vb = Kb + ELEMS;
        unsigned short* Ob = Vb + ELEMS;

        gemm_qkv_kernel<<<dim3(64, 8, 3), 256, 0, stream>>>(x, wq, wk, wv, Qb, Kb, Vb);
        attn12_kernel<<<1024, 256, 0, stream>>>(Qb, Kb, Vb, Ob);
        row2047_kernel<<<BATCH * NH, 256, 0, stream>>>(Vb, Ob);
        gemm_out_kernel<<<dim3(64, 8), 256, 0, stream>>>(Ob, wo, (float*)d_out);
    }
}